// Round 1
// baseline (3139.265 us; speedup 1.0000x reference)
//
#include <hip/hip_runtime.h>
#include <hip/hip_bf16.h>

#define NNODES 100000
#define NEDGES 1600000
#define CIN    128
#define HID    64
#define NGRAPH 64

// ---------------------------------------------------------------- utilities
__global__ void k_init_u32(unsigned* p, unsigned v, int n) {
    int i = blockIdx.x * 256 + threadIdx.x;
    if (i < n) p[i] = v;
}
__global__ void k_zero_f32(float* p, int n) {
    int i = blockIdx.x * 256 + threadIdx.x;
    if (i < n) p[i] = 0.f;
}

// ---------------------------------------------------------------- degrees
__global__ void k_count_deg(const int* __restrict__ ei, unsigned* deg, int E) {
    int e = blockIdx.x * 256 + threadIdx.x;
    if (e < E) atomicAdd(&deg[ei[E + e]], 1u);   // dst side
}
__global__ void k_dinv(const unsigned* __restrict__ deg, float* __restrict__ dinv, int n) {
    int i = blockIdx.x * 256 + threadIdx.x;
    if (i < n) dinv[i] = rsqrtf((float)deg[i]);
}

// ---------------------------------------------------------------- GEMM: A[n,K] @ W[K,64] (+addvec) -> out[n,64]
// block 256 threads, 64-row tile, 4x4 register tile, K chunked by 64.
template <int K>
__global__ __launch_bounds__(256) void k_gemm64(const float* __restrict__ A,
                                                const float* __restrict__ W,
                                                const float* __restrict__ addvec,
                                                float* __restrict__ out, int n) {
    __shared__ float wlds[64 * 64];
    __shared__ float alds[64 * 68];          // pad stride 68 (17*4): conflict-free-ish, 16B aligned

    const int tid = threadIdx.x;
    const int tc  = (tid & 15) * 4;          // col 0..60
    const int tr  = (tid >> 4) * 4;          // row 0..60
    const int row0 = blockIdx.x * 64;

    float acc[4][4];
    if (addvec) {
        float4 cv = *reinterpret_cast<const float4*>(&addvec[tc]);
        #pragma unroll
        for (int i = 0; i < 4; ++i) { acc[i][0]=cv.x; acc[i][1]=cv.y; acc[i][2]=cv.z; acc[i][3]=cv.w; }
    } else {
        #pragma unroll
        for (int i = 0; i < 4; ++i)
            #pragma unroll
            for (int j = 0; j < 4; ++j) acc[i][j] = 0.f;
    }

    for (int kc = 0; kc < K / 64; ++kc) {
        // stage W chunk [64][64]
        for (int idx = tid; idx < 64 * 16; idx += 256) {
            int r = idx >> 4, kk = (idx & 15) * 4;
            *reinterpret_cast<float4*>(&wlds[r * 64 + kk]) =
                *reinterpret_cast<const float4*>(&W[(kc * 64 + r) * 64 + kk]);
        }
        // stage A chunk [64][64]
        for (int idx = tid; idx < 64 * 16; idx += 256) {
            int r = idx >> 4, kk = (idx & 15) * 4;
            int row = row0 + r;
            float4 v = make_float4(0.f, 0.f, 0.f, 0.f);
            if (row < n) v = *reinterpret_cast<const float4*>(&A[row * K + kc * 64 + kk]);
            *reinterpret_cast<float4*>(&alds[r * 68 + kk]) = v;
        }
        __syncthreads();
        #pragma unroll 8
        for (int k = 0; k < 64; ++k) {
            float4 wv = *reinterpret_cast<const float4*>(&wlds[k * 64 + tc]);
            float av[4];
            #pragma unroll
            for (int i = 0; i < 4; ++i) av[i] = alds[(tr + i) * 68 + k];
            #pragma unroll
            for (int i = 0; i < 4; ++i) {
                acc[i][0] = fmaf(av[i], wv.x, acc[i][0]);
                acc[i][1] = fmaf(av[i], wv.y, acc[i][1]);
                acc[i][2] = fmaf(av[i], wv.z, acc[i][2]);
                acc[i][3] = fmaf(av[i], wv.w, acc[i][3]);
            }
        }
        __syncthreads();
    }

    #pragma unroll
    for (int i = 0; i < 4; ++i) {
        int row = row0 + tr + i;
        if (row < n)
            *reinterpret_cast<float4*>(&out[row * 64 + tc]) =
                make_float4(acc[i][0], acc[i][1], acc[i][2], acc[i][3]);
    }
}

// ---------------------------------------------------------------- self-loop init: agg = h * dinv^2
__global__ void k_self_init(const float* __restrict__ h, const float* __restrict__ dinv,
                            float* __restrict__ agg, int n) {
    int gid = blockIdx.x * 256 + threadIdx.x;
    int node = gid >> 4;
    if (node >= n) return;
    int c0 = (gid & 15) * 4;
    float w = dinv[node]; w *= w;
    float4 v = *reinterpret_cast<const float4*>(&h[node * 64 + c0]);
    *reinterpret_cast<float4*>(&agg[node * 64 + c0]) =
        make_float4(v.x * w, v.y * w, v.z * w, v.w * w);
}

// ---------------------------------------------------------------- edge scatter: agg[dst] += h[src]*dinv[s]*dinv[d]
__global__ void k_scatter(const int* __restrict__ ei, const float* __restrict__ h,
                          const float* __restrict__ dinv, float* agg, int E) {
    int gid = blockIdx.x * 256 + threadIdx.x;
    int e = gid >> 4;
    if (e >= E) return;
    int c0 = (gid & 15) * 4;
    int src = ei[e], dst = ei[E + e];
    float w = dinv[src] * dinv[dst];
    float4 v = *reinterpret_cast<const float4*>(&h[src * 64 + c0]);
    float* p = &agg[dst * 64 + c0];
    atomicAdd(p + 0, v.x * w);
    atomicAdd(p + 1, v.y * w);
    atomicAdd(p + 2, v.z * w);
    atomicAdd(p + 3, v.w * w);
}

// ---------------------------------------------------------------- bias + relu + BN stats (sum, sumsq)
__global__ __launch_bounds__(256) void k_bias_relu_stats(const float* __restrict__ agg,
                                                         const float* __restrict__ bias,
                                                         float* __restrict__ out,
                                                         float* bn_sum, float* bn_sq, int n) {
    int c  = threadIdx.x & 63;
    int rg = threadIdx.x >> 6;               // wave id 0..3
    int row0 = blockIdx.x * 128;
    float b = bias[c];
    float s = 0.f, q = 0.f;
    for (int i = 0; i < 32; ++i) {
        int r = row0 + rg + i * 4;
        if (r < n) {
            float v = agg[r * 64 + c] + b;
            v = fmaxf(v, 0.f);
            out[r * 64 + c] = v;
            s += v;
            q = fmaf(v, v, q);
        }
    }
    __shared__ float ls[4][64], lq[4][64];
    ls[rg][c] = s; lq[rg][c] = q;
    __syncthreads();
    if (threadIdx.x < 64) {
        atomicAdd(&bn_sum[c], ls[0][c] + ls[1][c] + ls[2][c] + ls[3][c]);
        atomicAdd(&bn_sq[c],  lq[0][c] + lq[1][c] + lq[2][c] + lq[3][c]);
    }
}

// ---------------------------------------------------------------- BN1 folded into W2:  BN(v)@W2 = v@W2eff + c2
__global__ void k_bn_fold_w2(const float* __restrict__ bn_sum, const float* __restrict__ bn_sq,
                             const float* __restrict__ gamma, const float* __restrict__ beta,
                             const float* __restrict__ W2, float* __restrict__ W2eff,
                             float* __restrict__ c2, int n) {
    __shared__ float sc[64], sh[64];
    int t = threadIdx.x;                      // 64 threads
    float inv_n = 1.0f / (float)n;
    float mu  = bn_sum[t] * inv_n;
    float var = bn_sq[t] * inv_n - mu * mu;
    float s = gamma[t] * rsqrtf(var + 1e-5f);
    sc[t] = s; sh[t] = beta[t] - mu * s;
    __syncthreads();
    float acc = 0.f;
    for (int k = 0; k < 64; ++k) {
        float w = W2[k * 64 + t];
        W2eff[k * 64 + t] = sc[k] * w;
        acc = fmaf(sh[k], w, acc);
    }
    c2[t] = acc;
}

// ---------------------------------------------------------------- BN2: just scale/shift per channel
__global__ void k_bn_final(const float* __restrict__ bn_sum, const float* __restrict__ bn_sq,
                           const float* __restrict__ gamma, const float* __restrict__ beta,
                           float* __restrict__ scale, float* __restrict__ shift, int n) {
    int t = threadIdx.x;
    if (t >= 64) return;
    float inv_n = 1.0f / (float)n;
    float mu  = bn_sum[t] * inv_n;
    float var = bn_sq[t] * inv_n - mu * mu;
    float s = gamma[t] * rsqrtf(var + 1e-5f);
    scale[t] = s; shift[t] = beta[t] - mu * s;
}

// ---------------------------------------------------------------- global mean pool (batch sorted) + BN2 affine
__device__ __forceinline__ int lower_bound_i(const int* a, int n, int v) {
    int lo = 0, hi = n;
    while (lo < hi) { int m = (lo + hi) >> 1; if (a[m] < v) lo = m + 1; else hi = m; }
    return lo;
}
__global__ __launch_bounds__(256) void k_pool(const float* __restrict__ h, const int* __restrict__ batch,
                                              const float* __restrict__ scale, const float* __restrict__ shift,
                                              float* __restrict__ gp, int n) {
    int g = blockIdx.x;
    int lo = lower_bound_i(batch, n, g);
    int hi = lower_bound_i(batch, n, g + 1);
    int c  = threadIdx.x & 63;
    int rg = threadIdx.x >> 6;
    float s = 0.f;
    for (int r = lo + rg; r < hi; r += 4) s += h[r * 64 + c];
    __shared__ float ls[4][64];
    ls[rg][c] = s;
    __syncthreads();
    if (threadIdx.x < 64) {
        int cnt = hi - lo;
        float S = ls[0][c] + ls[1][c] + ls[2][c] + ls[3][c];
        float v = (cnt > 0) ? (S / (float)cnt) * scale[c] + shift[c] : 0.f;
        gp[g * 64 + c] = v;
    }
}

// ---------------------------------------------------------------- MLP head: 64->128->64->32->16->1 per graph
__global__ __launch_bounds__(128) void k_mlp(const float* __restrict__ gp,
                                             const float* __restrict__ fW1, const float* __restrict__ fb1,
                                             const float* __restrict__ fW2, const float* __restrict__ fb2,
                                             const float* __restrict__ fW3, const float* __restrict__ fb3,
                                             const float* __restrict__ fW4, const float* __restrict__ fb4,
                                             const float* __restrict__ oW,  const float* __restrict__ ob,
                                             float* __restrict__ out) {
    int g = blockIdx.x;
    int t = threadIdx.x;
    __shared__ float a[128], bbuf[128];
    if (t < 64) a[t] = gp[g * 64 + t];
    __syncthreads();
    { // 64 -> 128
        float acc = fb1[t];
        for (int k = 0; k < 64; ++k) acc = fmaf(a[k], fW1[k * 128 + t], acc);
        bbuf[t] = fmaxf(acc, 0.f);
    }
    __syncthreads();
    if (t < 64) { // 128 -> 64
        float acc = fb2[t];
        for (int k = 0; k < 128; ++k) acc = fmaf(bbuf[k], fW2[k * 64 + t], acc);
        a[t] = fmaxf(acc, 0.f);
    }
    __syncthreads();
    if (t < 32) { // 64 -> 32
        float acc = fb3[t];
        for (int k = 0; k < 64; ++k) acc = fmaf(a[k], fW3[k * 32 + t], acc);
        bbuf[t] = fmaxf(acc, 0.f);
    }
    __syncthreads();
    if (t < 16) { // 32 -> 16
        float acc = fb4[t];
        for (int k = 0; k < 32; ++k) acc = fmaf(bbuf[k], fW4[k * 16 + t], acc);
        a[t] = fmaxf(acc, 0.f);
    }
    __syncthreads();
    if (t == 0) { // 16 -> 1
        float acc = ob[0];
        for (int k = 0; k < 16; ++k) acc = fmaf(a[k], oW[k], acc);
        out[g] = acc;
    }
}

// ---------------------------------------------------------------- launch
extern "C" void kernel_launch(void* const* d_in, const int* in_sizes, int n_in,
                              void* d_out, int out_size, void* d_ws, size_t ws_size,
                              hipStream_t stream) {
    const float* x      = (const float*)d_in[0];
    const int*   ei     = (const int*)  d_in[1];
    const int*   batch  = (const int*)  d_in[2];
    const float* W1     = (const float*)d_in[3];
    const float* b1     = (const float*)d_in[4];
    const float* W2     = (const float*)d_in[5];
    const float* b2     = (const float*)d_in[6];
    const float* gamma1 = (const float*)d_in[7];
    const float* beta1  = (const float*)d_in[8];
    const float* gamma2 = (const float*)d_in[9];
    const float* beta2  = (const float*)d_in[10];
    const float* fW1    = (const float*)d_in[11];
    const float* fb1    = (const float*)d_in[12];
    const float* fW2    = (const float*)d_in[13];
    const float* fb2    = (const float*)d_in[14];
    const float* fW3    = (const float*)d_in[15];
    const float* fb3    = (const float*)d_in[16];
    const float* fW4    = (const float*)d_in[17];
    const float* fb4    = (const float*)d_in[18];
    const float* oW     = (const float*)d_in[19];
    const float* ob     = (const float*)d_in[20];
    float* out = (float*)d_out;

    const int N = NNODES, E = NEDGES, G = NGRAPH;

    // workspace layout (floats)
    float* bufA   = (float*)d_ws;                 // N*64
    float* bufB   = bufA + (size_t)N * 64;        // N*64
    unsigned* deg = (unsigned*)(bufB + (size_t)N * 64);  // N
    float* dinv   = (float*)(deg + N);            // N
    float* bn1s   = dinv + N;                     // 64
    float* bn1q   = bn1s + 64;                    // 64
    float* bn2s   = bn1q + 64;                    // 64
    float* bn2q   = bn2s + 64;                    // 64
    float* scale2 = bn2q + 64;                    // 64
    float* shift2 = scale2 + 64;                  // 64
    float* W2eff  = shift2 + 64;                  // 4096
    float* c2     = W2eff + 4096;                 // 64
    float* gpool  = c2 + 64;                      // G*64

    // --- degree / norm ---
    k_init_u32<<<(N + 255) / 256, 256, 0, stream>>>(deg, 1u, N);
    k_zero_f32<<<1, 256, 0, stream>>>(bn1s, 256);   // zeros bn1s..bn2q (contiguous 256 floats)
    k_count_deg<<<(E + 255) / 256, 256, 0, stream>>>(ei, deg, E);
    k_dinv<<<(N + 255) / 256, 256, 0, stream>>>(deg, dinv, N);

    // --- layer 1: h1 = x @ W1 ---
    k_gemm64<128><<<(N + 63) / 64, 256, 0, stream>>>(x, W1, nullptr, bufA, N);
    k_self_init<<<(N * 16 + 255) / 256, 256, 0, stream>>>(bufA, dinv, bufB, N);
    k_scatter<<<(E * 16 + 255) / 256, 256, 0, stream>>>(ei, bufA, dinv, bufB, E);
    k_bias_relu_stats<<<(N + 127) / 128, 256, 0, stream>>>(bufB, b1, bufA, bn1s, bn1q, N);
    k_bn_fold_w2<<<1, 64, 0, stream>>>(bn1s, bn1q, gamma1, beta1, W2, W2eff, c2, N);

    // --- layer 2: h2 = BN1(h1r) @ W2 = h1r @ W2eff + c2 ---
    k_gemm64<64><<<(N + 63) / 64, 256, 0, stream>>>(bufA, W2eff, c2, bufB, N);
    k_self_init<<<(N * 16 + 255) / 256, 256, 0, stream>>>(bufB, dinv, bufA, N);
    k_scatter<<<(E * 16 + 255) / 256, 256, 0, stream>>>(ei, bufB, dinv, bufA, E);
    k_bias_relu_stats<<<(N + 127) / 128, 256, 0, stream>>>(bufA, b2, bufB, bn2s, bn2q, N);
    k_bn_final<<<1, 64, 0, stream>>>(bn2s, bn2q, gamma2, beta2, scale2, shift2, N);

    // --- pool + MLP ---
    k_pool<<<G, 256, 0, stream>>>(bufB, batch, scale2, shift2, gpool, N);
    k_mlp<<<G, 128, 0, stream>>>(gpool, fW1, fb1, fW2, fb2, fW3, fb3, fW4, fb4, oW, ob, out);
}

// Round 2
// 694.462 us; speedup vs baseline: 4.5204x; 4.5204x over previous
//
#include <hip/hip_runtime.h>
#include <hip/hip_bf16.h>

#define NNODES 100000
#define NEDGES 1600000
#define CIN    128
#define HID    64
#define NGRAPH 64

// ---------------------------------------------------------------- utilities
__global__ void k_zero_u32(unsigned* p, int n) {
    int i = blockIdx.x * 256 + threadIdx.x;
    if (i < n) p[i] = 0u;
}
__global__ void k_zero_f32(float* p, int n) {
    int i = blockIdx.x * 256 + threadIdx.x;
    if (i < n) p[i] = 0.f;
}

// ---------------------------------------------------------------- degrees
__global__ void k_count_deg(const int* __restrict__ ei, unsigned* indeg, int E) {
    int e = blockIdx.x * 256 + threadIdx.x;
    if (e < E) atomicAdd(&indeg[ei[E + e]], 1u);   // dst side
}
__global__ void k_dinv(const unsigned* __restrict__ indeg, float* __restrict__ dinv, int n) {
    int i = blockIdx.x * 256 + threadIdx.x;
    if (i < n) dinv[i] = rsqrtf((float)(indeg[i] + 1u));   // +1 self-loop
}

// ---------------------------------------------------------------- CSR build: scan + fill
__global__ __launch_bounds__(256) void k_block_reduce(const unsigned* __restrict__ v, unsigned* bsum, int n) {
    __shared__ unsigned s[256];
    int i = blockIdx.x * 256 + threadIdx.x;
    s[threadIdx.x] = (i < n) ? v[i] : 0u;
    __syncthreads();
    for (int off = 128; off > 0; off >>= 1) {
        if (threadIdx.x < off) s[threadIdx.x] += s[threadIdx.x + off];
        __syncthreads();
    }
    if (threadIdx.x == 0) bsum[blockIdx.x] = s[0];
}
// single block of 512: exclusive scan of nb block sums
__global__ __launch_bounds__(512) void k_scan_bsum(const unsigned* __restrict__ bsum, unsigned* boff, int nb) {
    __shared__ unsigned s[512];
    int t = threadIdx.x;
    unsigned mine = (t < nb) ? bsum[t] : 0u;
    s[t] = mine;
    __syncthreads();
    for (int off = 1; off < 512; off <<= 1) {
        unsigned u = (t >= off) ? s[t - off] : 0u;
        __syncthreads();
        s[t] += u;
        __syncthreads();
    }
    if (t < nb) boff[t] = s[t] - mine;   // exclusive
}
__global__ __launch_bounds__(256) void k_scan_final(const unsigned* __restrict__ indeg,
                                                    const unsigned* __restrict__ boff,
                                                    unsigned* __restrict__ rowptr,
                                                    unsigned* __restrict__ cursor, int n) {
    __shared__ unsigned s[256];
    int i = blockIdx.x * 256 + threadIdx.x;
    unsigned v = (i < n) ? indeg[i] : 0u;
    s[threadIdx.x] = v;
    __syncthreads();
    for (int off = 1; off < 256; off <<= 1) {
        unsigned u = (threadIdx.x >= off) ? s[threadIdx.x - off] : 0u;
        __syncthreads();
        s[threadIdx.x] += u;
        __syncthreads();
    }
    if (i < n) {
        unsigned ex = s[threadIdx.x] - v + boff[blockIdx.x];
        rowptr[i] = ex;
        cursor[i] = ex;
        if (i == n - 1) rowptr[n] = s[threadIdx.x] + boff[blockIdx.x];   // == E
    }
}
__global__ void k_fill(const int* __restrict__ ei, unsigned* cursor,
                       unsigned* __restrict__ colidx, int E) {
    int e = blockIdx.x * 256 + threadIdx.x;
    if (e >= E) return;
    int src = ei[e], dst = ei[E + e];
    unsigned pos = atomicAdd(&cursor[dst], 1u);
    colidx[pos] = (unsigned)src;
}

// ---------------------------------------------------------------- GEMM: A[n,K] @ W[K,64] (+addvec) *rowscale -> out[n,64]
template <int K>
__global__ __launch_bounds__(256) void k_gemm64(const float* __restrict__ A,
                                                const float* __restrict__ W,
                                                const float* __restrict__ addvec,
                                                const float* __restrict__ rowscale,
                                                float* __restrict__ out, int n) {
    __shared__ float wlds[64 * 64];
    __shared__ float alds[64 * 68];

    const int tid = threadIdx.x;
    const int tc  = (tid & 15) * 4;
    const int tr  = (tid >> 4) * 4;
    const int row0 = blockIdx.x * 64;

    float acc[4][4];
    if (addvec) {
        float4 cv = *reinterpret_cast<const float4*>(&addvec[tc]);
        #pragma unroll
        for (int i = 0; i < 4; ++i) { acc[i][0]=cv.x; acc[i][1]=cv.y; acc[i][2]=cv.z; acc[i][3]=cv.w; }
    } else {
        #pragma unroll
        for (int i = 0; i < 4; ++i)
            #pragma unroll
            for (int j = 0; j < 4; ++j) acc[i][j] = 0.f;
    }

    for (int kc = 0; kc < K / 64; ++kc) {
        for (int idx = tid; idx < 64 * 16; idx += 256) {
            int r = idx >> 4, kk = (idx & 15) * 4;
            *reinterpret_cast<float4*>(&wlds[r * 64 + kk]) =
                *reinterpret_cast<const float4*>(&W[(kc * 64 + r) * 64 + kk]);
        }
        for (int idx = tid; idx < 64 * 16; idx += 256) {
            int r = idx >> 4, kk = (idx & 15) * 4;
            int row = row0 + r;
            float4 v = make_float4(0.f, 0.f, 0.f, 0.f);
            if (row < n) v = *reinterpret_cast<const float4*>(&A[row * K + kc * 64 + kk]);
            *reinterpret_cast<float4*>(&alds[r * 68 + kk]) = v;
        }
        __syncthreads();
        #pragma unroll 8
        for (int k = 0; k < 64; ++k) {
            float4 wv = *reinterpret_cast<const float4*>(&wlds[k * 64 + tc]);
            float av[4];
            #pragma unroll
            for (int i = 0; i < 4; ++i) av[i] = alds[(tr + i) * 68 + k];
            #pragma unroll
            for (int i = 0; i < 4; ++i) {
                acc[i][0] = fmaf(av[i], wv.x, acc[i][0]);
                acc[i][1] = fmaf(av[i], wv.y, acc[i][1]);
                acc[i][2] = fmaf(av[i], wv.z, acc[i][2]);
                acc[i][3] = fmaf(av[i], wv.w, acc[i][3]);
            }
        }
        __syncthreads();
    }

    #pragma unroll
    for (int i = 0; i < 4; ++i) {
        int row = row0 + tr + i;
        if (row < n) {
            float f = rowscale ? rowscale[row] : 1.0f;
            *reinterpret_cast<float4*>(&out[row * 64 + tc]) =
                make_float4(acc[i][0]*f, acc[i][1]*f, acc[i][2]*f, acc[i][3]*f);
        }
    }
}

// ---------------------------------------------------------------- CSR gather: agg[d] = dinv[d]*(hd[d] + sum_in hd[src])
__global__ __launch_bounds__(256) void k_gather(const unsigned* __restrict__ rowptr,
                                                const unsigned* __restrict__ colidx,
                                                const float* __restrict__ hd,
                                                const float* __restrict__ dinv,
                                                float* __restrict__ agg, int n) {
    int gid = blockIdx.x * 256 + threadIdx.x;
    int node = gid >> 4;
    if (node >= n) return;
    int c0 = (gid & 15) * 4;
    unsigned lo = rowptr[node], hi = rowptr[node + 1];
    float4 acc = *reinterpret_cast<const float4*>(&hd[node * 64 + c0]);
    for (unsigned j = lo; j < hi; ++j) {
        unsigned src = colidx[j];
        float4 v = *reinterpret_cast<const float4*>(&hd[src * 64 + c0]);
        acc.x += v.x; acc.y += v.y; acc.z += v.z; acc.w += v.w;
    }
    float w = dinv[node];
    *reinterpret_cast<float4*>(&agg[node * 64 + c0]) =
        make_float4(acc.x * w, acc.y * w, acc.z * w, acc.w * w);
}

// ---------------------------------------------------------------- bias + relu (in-place) + BN stats
__global__ __launch_bounds__(256) void k_bias_relu_stats(float* __restrict__ buf,
                                                         const float* __restrict__ bias,
                                                         float* bn_sum, float* bn_sq, int n) {
    int c  = threadIdx.x & 63;
    int rg = threadIdx.x >> 6;
    int row0 = blockIdx.x * 128;
    float b = bias[c];
    float s = 0.f, q = 0.f;
    for (int i = 0; i < 32; ++i) {
        int r = row0 + rg + i * 4;
        if (r < n) {
            float v = buf[r * 64 + c] + b;
            v = fmaxf(v, 0.f);
            buf[r * 64 + c] = v;
            s += v;
            q = fmaf(v, v, q);
        }
    }
    __shared__ float ls[4][64], lq[4][64];
    ls[rg][c] = s; lq[rg][c] = q;
    __syncthreads();
    if (threadIdx.x < 64) {
        atomicAdd(&bn_sum[c], ls[0][c] + ls[1][c] + ls[2][c] + ls[3][c]);
        atomicAdd(&bn_sq[c],  lq[0][c] + lq[1][c] + lq[2][c] + lq[3][c]);
    }
}

// ---------------------------------------------------------------- BN1 folded into W2
__global__ void k_bn_fold_w2(const float* __restrict__ bn_sum, const float* __restrict__ bn_sq,
                             const float* __restrict__ gamma, const float* __restrict__ beta,
                             const float* __restrict__ W2, float* __restrict__ W2eff,
                             float* __restrict__ c2, int n) {
    __shared__ float sc[64], sh[64];
    int t = threadIdx.x;
    float inv_n = 1.0f / (float)n;
    float mu  = bn_sum[t] * inv_n;
    float var = bn_sq[t] * inv_n - mu * mu;
    float s = gamma[t] * rsqrtf(var + 1e-5f);
    sc[t] = s; sh[t] = beta[t] - mu * s;
    __syncthreads();
    float acc = 0.f;
    for (int k = 0; k < 64; ++k) {
        float w = W2[k * 64 + t];
        W2eff[k * 64 + t] = sc[k] * w;
        acc = fmaf(sh[k], w, acc);
    }
    c2[t] = acc;
}

// ---------------------------------------------------------------- BN2 scale/shift
__global__ void k_bn_final(const float* __restrict__ bn_sum, const float* __restrict__ bn_sq,
                           const float* __restrict__ gamma, const float* __restrict__ beta,
                           float* __restrict__ scale, float* __restrict__ shift, int n) {
    int t = threadIdx.x;
    if (t >= 64) return;
    float inv_n = 1.0f / (float)n;
    float mu  = bn_sum[t] * inv_n;
    float var = bn_sq[t] * inv_n - mu * mu;
    float s = gamma[t] * rsqrtf(var + 1e-5f);
    scale[t] = s; shift[t] = beta[t] - mu * s;
}

// ---------------------------------------------------------------- pool + BN2 affine
__device__ __forceinline__ int lower_bound_i(const int* a, int n, int v) {
    int lo = 0, hi = n;
    while (lo < hi) { int m = (lo + hi) >> 1; if (a[m] < v) lo = m + 1; else hi = m; }
    return lo;
}
__global__ __launch_bounds__(256) void k_pool(const float* __restrict__ h, const int* __restrict__ batch,
                                              const float* __restrict__ scale, const float* __restrict__ shift,
                                              float* __restrict__ gp, int n) {
    int g = blockIdx.x;
    int lo = lower_bound_i(batch, n, g);
    int hi = lower_bound_i(batch, n, g + 1);
    int c  = threadIdx.x & 63;
    int rg = threadIdx.x >> 6;
    float s = 0.f;
    for (int r = lo + rg; r < hi; r += 4) s += h[r * 64 + c];
    __shared__ float ls[4][64];
    ls[rg][c] = s;
    __syncthreads();
    if (threadIdx.x < 64) {
        int cnt = hi - lo;
        float S = ls[0][c] + ls[1][c] + ls[2][c] + ls[3][c];
        float v = (cnt > 0) ? (S / (float)cnt) * scale[c] + shift[c] : 0.f;
        gp[g * 64 + c] = v;
    }
}

// ---------------------------------------------------------------- MLP head
__global__ __launch_bounds__(128) void k_mlp(const float* __restrict__ gp,
                                             const float* __restrict__ fW1, const float* __restrict__ fb1,
                                             const float* __restrict__ fW2, const float* __restrict__ fb2,
                                             const float* __restrict__ fW3, const float* __restrict__ fb3,
                                             const float* __restrict__ fW4, const float* __restrict__ fb4,
                                             const float* __restrict__ oW,  const float* __restrict__ ob,
                                             float* __restrict__ out) {
    int g = blockIdx.x;
    int t = threadIdx.x;
    __shared__ float a[128], bbuf[128];
    if (t < 64) a[t] = gp[g * 64 + t];
    __syncthreads();
    {
        float acc = fb1[t];
        for (int k = 0; k < 64; ++k) acc = fmaf(a[k], fW1[k * 128 + t], acc);
        bbuf[t] = fmaxf(acc, 0.f);
    }
    __syncthreads();
    if (t < 64) {
        float acc = fb2[t];
        for (int k = 0; k < 128; ++k) acc = fmaf(bbuf[k], fW2[k * 64 + t], acc);
        a[t] = fmaxf(acc, 0.f);
    }
    __syncthreads();
    if (t < 32) {
        float acc = fb3[t];
        for (int k = 0; k < 64; ++k) acc = fmaf(a[k], fW3[k * 32 + t], acc);
        bbuf[t] = fmaxf(acc, 0.f);
    }
    __syncthreads();
    if (t < 16) {
        float acc = fb4[t];
        for (int k = 0; k < 32; ++k) acc = fmaf(bbuf[k], fW4[k * 16 + t], acc);
        a[t] = fmaxf(acc, 0.f);
    }
    __syncthreads();
    if (t == 0) {
        float acc = ob[0];
        for (int k = 0; k < 16; ++k) acc = fmaf(a[k], oW[k], acc);
        out[g] = acc;
    }
}

// ---------------------------------------------------------------- launch
extern "C" void kernel_launch(void* const* d_in, const int* in_sizes, int n_in,
                              void* d_out, int out_size, void* d_ws, size_t ws_size,
                              hipStream_t stream) {
    const float* x      = (const float*)d_in[0];
    const int*   ei     = (const int*)  d_in[1];
    const int*   batch  = (const int*)  d_in[2];
    const float* W1     = (const float*)d_in[3];
    const float* b1     = (const float*)d_in[4];
    const float* W2     = (const float*)d_in[5];
    const float* b2     = (const float*)d_in[6];
    const float* gamma1 = (const float*)d_in[7];
    const float* beta1  = (const float*)d_in[8];
    const float* gamma2 = (const float*)d_in[9];
    const float* beta2  = (const float*)d_in[10];
    const float* fW1    = (const float*)d_in[11];
    const float* fb1    = (const float*)d_in[12];
    const float* fW2    = (const float*)d_in[13];
    const float* fb2    = (const float*)d_in[14];
    const float* fW3    = (const float*)d_in[15];
    const float* fb3    = (const float*)d_in[16];
    const float* fW4    = (const float*)d_in[17];
    const float* fb4    = (const float*)d_in[18];
    const float* oW     = (const float*)d_in[19];
    const float* ob     = (const float*)d_in[20];
    float* out = (float*)d_out;

    const int N = NNODES, E = NEDGES, G = NGRAPH;
    const int NB = (N + 255) / 256;   // 391 scan blocks

    // workspace layout
    float*    bufA   = (float*)d_ws;                       // N*64
    float*    bufB   = bufA + (size_t)N * 64;              // N*64
    unsigned* indeg  = (unsigned*)(bufB + (size_t)N * 64); // N
    float*    dinv   = (float*)(indeg + N);                // N
    unsigned* rowptr = (unsigned*)(dinv + N);              // N+1
    unsigned* cursor = rowptr + (N + 1);                   // N
    unsigned* colidx = cursor + N;                         // E
    unsigned* bsum   = colidx + E;                         // 512
    unsigned* boff   = bsum + 512;                         // 512
    float*    bn1s   = (float*)(boff + 512);               // 64
    float*    bn1q   = bn1s + 64;                          // 64
    float*    bn2s   = bn1q + 64;                          // 64
    float*    bn2q   = bn2s + 64;                          // 64
    float*    scale2 = bn2q + 64;                          // 64
    float*    shift2 = scale2 + 64;                        // 64
    float*    W2eff  = shift2 + 64;                        // 4096
    float*    c2     = W2eff + 4096;                       // 64
    float*    gpool  = c2 + 64;                            // G*64

    // --- degrees + CSR build (once, shared by both layers) ---
    k_zero_u32<<<NB, 256, 0, stream>>>(indeg, N);
    k_zero_f32<<<1, 256, 0, stream>>>(bn1s, 256);
    k_count_deg<<<(E + 255) / 256, 256, 0, stream>>>(ei, indeg, E);
    k_dinv<<<NB, 256, 0, stream>>>(indeg, dinv, N);
    k_block_reduce<<<NB, 256, 0, stream>>>(indeg, bsum, N);
    k_scan_bsum<<<1, 512, 0, stream>>>(bsum, boff, NB);
    k_scan_final<<<NB, 256, 0, stream>>>(indeg, boff, rowptr, cursor, N);
    k_fill<<<(E + 255) / 256, 256, 0, stream>>>(ei, cursor, colidx, E);

    // --- layer 1: hd1 = (x @ W1) * dinv ---
    k_gemm64<128><<<(N + 63) / 64, 256, 0, stream>>>(x, W1, nullptr, dinv, bufA, N);
    k_gather<<<(N * 16 + 255) / 256, 256, 0, stream>>>(rowptr, colidx, bufA, dinv, bufB, N);
    k_bias_relu_stats<<<(N + 127) / 128, 256, 0, stream>>>(bufB, b1, bn1s, bn1q, N);
    k_bn_fold_w2<<<1, 64, 0, stream>>>(bn1s, bn1q, gamma1, beta1, W2, W2eff, c2, N);

    // --- layer 2: hd2 = (act1 @ W2eff + c2) * dinv ---
    k_gemm64<64><<<(N + 63) / 64, 256, 0, stream>>>(bufB, W2eff, c2, dinv, bufA, N);
    k_gather<<<(N * 16 + 255) / 256, 256, 0, stream>>>(rowptr, colidx, bufA, dinv, bufB, N);
    k_bias_relu_stats<<<(N + 127) / 128, 256, 0, stream>>>(bufB, b2, bn2s, bn2q, N);
    k_bn_final<<<1, 64, 0, stream>>>(bn2s, bn2q, gamma2, beta2, scale2, shift2, N);

    // --- pool + MLP ---
    k_pool<<<G, 256, 0, stream>>>(bufB, batch, scale2, shift2, gpool, N);
    k_mlp<<<G, 128, 0, stream>>>(gpool, fW1, fb1, fW2, fb2, fW3, fb3, fW4, fb4, oW, ob, out);
}

// Round 3
// 597.123 us; speedup vs baseline: 5.2573x; 1.1630x over previous
//
#include <hip/hip_runtime.h>
#include <hip/hip_bf16.h>

#define NNODES 100000
#define NEDGES 1600000
#define NGRAPH 64

// ---------------------------------------------------------------- degrees
__global__ void k_count_deg(const int* __restrict__ ei, unsigned* indeg, int E) {
    int e = blockIdx.x * 256 + threadIdx.x;
    if (e < E) atomicAdd(&indeg[ei[E + e]], 1u);   // dst side
}

// ---------------------------------------------------------------- CSR build: scan
__global__ __launch_bounds__(256) void k_block_reduce(const unsigned* __restrict__ v, unsigned* bsum, int n) {
    __shared__ unsigned s[256];
    int i = blockIdx.x * 256 + threadIdx.x;
    s[threadIdx.x] = (i < n) ? v[i] : 0u;
    __syncthreads();
    for (int off = 128; off > 0; off >>= 1) {
        if (threadIdx.x < off) s[threadIdx.x] += s[threadIdx.x + off];
        __syncthreads();
    }
    if (threadIdx.x == 0) bsum[blockIdx.x] = s[0];
}
__global__ __launch_bounds__(512) void k_scan_bsum(const unsigned* __restrict__ bsum, unsigned* boff, int nb) {
    __shared__ unsigned s[512];
    int t = threadIdx.x;
    unsigned mine = (t < nb) ? bsum[t] : 0u;
    s[t] = mine;
    __syncthreads();
    for (int off = 1; off < 512; off <<= 1) {
        unsigned u = (t >= off) ? s[t - off] : 0u;
        __syncthreads();
        s[t] += u;
        __syncthreads();
    }
    if (t < nb) boff[t] = s[t] - mine;   // exclusive
}
// final scan; also emits dinv = rsqrt(indeg+1) (self-loop)
__global__ __launch_bounds__(256) void k_scan_final(const unsigned* __restrict__ indeg,
                                                    const unsigned* __restrict__ boff,
                                                    unsigned* __restrict__ rowptr,
                                                    unsigned* __restrict__ cursor,
                                                    float* __restrict__ dinv, int n) {
    __shared__ unsigned s[256];
    int i = blockIdx.x * 256 + threadIdx.x;
    unsigned v = (i < n) ? indeg[i] : 0u;
    s[threadIdx.x] = v;
    __syncthreads();
    for (int off = 1; off < 256; off <<= 1) {
        unsigned u = (threadIdx.x >= off) ? s[threadIdx.x - off] : 0u;
        __syncthreads();
        s[threadIdx.x] += u;
        __syncthreads();
    }
    if (i < n) {
        unsigned ex = s[threadIdx.x] - v + boff[blockIdx.x];
        rowptr[i] = ex;
        cursor[i] = ex;
        dinv[i]   = rsqrtf((float)(v + 1u));
        if (i == n - 1) rowptr[n] = s[threadIdx.x] + boff[blockIdx.x];
    }
}

// ---------------------------------------------------------------- fused GEMM1 (x@W1 *dinv) + CSR fill
// every 5th block is a GEMM tile (1563 of 7813); the rest (6250) fill colidx.
__global__ __launch_bounds__(256) void k_gemm1_fill(const float* __restrict__ A,
                                                    const float* __restrict__ W,
                                                    const float* __restrict__ rowscale,
                                                    float* __restrict__ out,
                                                    const int* __restrict__ ei,
                                                    unsigned* __restrict__ cursor,
                                                    unsigned* __restrict__ colidx) {
    __shared__ float wlds[64 * 64];
    __shared__ float alds[64 * 68];
    const int b = blockIdx.x;
    const int tid = threadIdx.x;

    if (b % 5 == 0) {
        // ---------------- GEMM tile, rows [g*64, g*64+64), K=128
        const int row0 = (b / 5) * 64;
        const int tc = (tid & 15) * 4;
        const int tr = (tid >> 4) * 4;
        float acc[4][4];
        #pragma unroll
        for (int i = 0; i < 4; ++i)
            #pragma unroll
            for (int j = 0; j < 4; ++j) acc[i][j] = 0.f;

        for (int kc = 0; kc < 2; ++kc) {
            for (int idx = tid; idx < 64 * 16; idx += 256) {
                int r = idx >> 4, kk = (idx & 15) * 4;
                *reinterpret_cast<float4*>(&wlds[r * 64 + kk]) =
                    *reinterpret_cast<const float4*>(&W[(kc * 64 + r) * 64 + kk]);
            }
            for (int idx = tid; idx < 64 * 16; idx += 256) {
                int r = idx >> 4, kk = (idx & 15) * 4;
                int row = row0 + r;
                float4 v = make_float4(0.f, 0.f, 0.f, 0.f);
                if (row < NNODES) v = *reinterpret_cast<const float4*>(&A[row * 128 + kc * 64 + kk]);
                *reinterpret_cast<float4*>(&alds[r * 68 + kk]) = v;
            }
            __syncthreads();
            #pragma unroll 8
            for (int k = 0; k < 64; ++k) {
                float4 wv = *reinterpret_cast<const float4*>(&wlds[k * 64 + tc]);
                float av[4];
                #pragma unroll
                for (int i = 0; i < 4; ++i) av[i] = alds[(tr + i) * 68 + k];
                #pragma unroll
                for (int i = 0; i < 4; ++i) {
                    acc[i][0] = fmaf(av[i], wv.x, acc[i][0]);
                    acc[i][1] = fmaf(av[i], wv.y, acc[i][1]);
                    acc[i][2] = fmaf(av[i], wv.z, acc[i][2]);
                    acc[i][3] = fmaf(av[i], wv.w, acc[i][3]);
                }
            }
            __syncthreads();
        }
        #pragma unroll
        for (int i = 0; i < 4; ++i) {
            int row = row0 + tr + i;
            if (row < NNODES) {
                float f = rowscale[row];
                *reinterpret_cast<float4*>(&out[row * 64 + tc]) =
                    make_float4(acc[i][0]*f, acc[i][1]*f, acc[i][2]*f, acc[i][3]*f);
            }
        }
    } else {
        // ---------------- CSR fill
        int fi = b - (b + 4) / 5;
        int e = fi * 256 + tid;
        if (e < NEDGES) {
            int src = ei[e], dst = ei[NEDGES + e];
            unsigned pos = atomicAdd(&cursor[dst], 1u);
            colidx[pos] = (unsigned)src;
        }
    }
}

// ---------------------------------------------------------------- standalone GEMM for layer 2
template <int K>
__global__ __launch_bounds__(256) void k_gemm64(const float* __restrict__ A,
                                                const float* __restrict__ W,
                                                const float* __restrict__ addvec,
                                                const float* __restrict__ rowscale,
                                                float* __restrict__ out, int n) {
    __shared__ float wlds[64 * 64];
    __shared__ float alds[64 * 68];
    const int tid = threadIdx.x;
    const int tc  = (tid & 15) * 4;
    const int tr  = (tid >> 4) * 4;
    const int row0 = blockIdx.x * 64;

    float acc[4][4];
    float4 cv = *reinterpret_cast<const float4*>(&addvec[tc]);
    #pragma unroll
    for (int i = 0; i < 4; ++i) { acc[i][0]=cv.x; acc[i][1]=cv.y; acc[i][2]=cv.z; acc[i][3]=cv.w; }

    for (int kc = 0; kc < K / 64; ++kc) {
        for (int idx = tid; idx < 64 * 16; idx += 256) {
            int r = idx >> 4, kk = (idx & 15) * 4;
            *reinterpret_cast<float4*>(&wlds[r * 64 + kk]) =
                *reinterpret_cast<const float4*>(&W[(kc * 64 + r) * 64 + kk]);
        }
        for (int idx = tid; idx < 64 * 16; idx += 256) {
            int r = idx >> 4, kk = (idx & 15) * 4;
            int row = row0 + r;
            float4 v = make_float4(0.f, 0.f, 0.f, 0.f);
            if (row < n) v = *reinterpret_cast<const float4*>(&A[row * K + kc * 64 + kk]);
            *reinterpret_cast<float4*>(&alds[r * 68 + kk]) = v;
        }
        __syncthreads();
        #pragma unroll 8
        for (int k = 0; k < 64; ++k) {
            float4 wv = *reinterpret_cast<const float4*>(&wlds[k * 64 + tc]);
            float av[4];
            #pragma unroll
            for (int i = 0; i < 4; ++i) av[i] = alds[(tr + i) * 68 + k];
            #pragma unroll
            for (int i = 0; i < 4; ++i) {
                acc[i][0] = fmaf(av[i], wv.x, acc[i][0]);
                acc[i][1] = fmaf(av[i], wv.y, acc[i][1]);
                acc[i][2] = fmaf(av[i], wv.z, acc[i][2]);
                acc[i][3] = fmaf(av[i], wv.w, acc[i][3]);
            }
        }
        __syncthreads();
    }
    #pragma unroll
    for (int i = 0; i < 4; ++i) {
        int row = row0 + tr + i;
        if (row < n) {
            float f = rowscale[row];
            *reinterpret_cast<float4*>(&out[row * 64 + tc]) =
                make_float4(acc[i][0]*f, acc[i][1]*f, acc[i][2]*f, acc[i][3]*f);
        }
    }
}

// ---------------------------------------------------------------- fused gather + bias + relu + BN stats
// act[d] = relu(dinv[d]*(hd[d] + sum_in hd[src]) + b); accumulates per-channel sum/sumsq.
__global__ __launch_bounds__(256) void k_gather_fused(const unsigned* __restrict__ rowptr,
                                                      const unsigned* __restrict__ colidx,
                                                      const float* __restrict__ hd,
                                                      const float* __restrict__ dinv,
                                                      const float* __restrict__ bias,
                                                      float* __restrict__ act,
                                                      float* bn_sum, float* bn_sq, int n) {
    const int tid   = threadIdx.x;
    const int grp   = tid >> 4;          // 0..15 (node slot within tile)
    const int c0    = (tid & 15) * 4;    // channel group
    float4 bv = *reinterpret_cast<const float4*>(&bias[c0]);
    float s0=0.f,s1=0.f,s2=0.f,s3=0.f, q0=0.f,q1=0.f,q2=0.f,q3=0.f;

    #pragma unroll
    for (int it = 0; it < 8; ++it) {
        int node = (blockIdx.x * 8 + it) * 16 + grp;
        if (node < n) {
            unsigned lo = rowptr[node], hi = rowptr[node + 1];
            float4 acc = *reinterpret_cast<const float4*>(&hd[(size_t)node * 64 + c0]);
            unsigned j = lo;
            for (; j + 4 <= hi; j += 4) {
                unsigned a0 = colidx[j], a1 = colidx[j+1], a2 = colidx[j+2], a3 = colidx[j+3];
                float4 v0 = *reinterpret_cast<const float4*>(&hd[(size_t)a0 * 64 + c0]);
                float4 v1 = *reinterpret_cast<const float4*>(&hd[(size_t)a1 * 64 + c0]);
                float4 v2 = *reinterpret_cast<const float4*>(&hd[(size_t)a2 * 64 + c0]);
                float4 v3 = *reinterpret_cast<const float4*>(&hd[(size_t)a3 * 64 + c0]);
                acc.x += (v0.x + v1.x) + (v2.x + v3.x);
                acc.y += (v0.y + v1.y) + (v2.y + v3.y);
                acc.z += (v0.z + v1.z) + (v2.z + v3.z);
                acc.w += (v0.w + v1.w) + (v2.w + v3.w);
            }
            for (; j < hi; ++j) {
                unsigned a0 = colidx[j];
                float4 v0 = *reinterpret_cast<const float4*>(&hd[(size_t)a0 * 64 + c0]);
                acc.x += v0.x; acc.y += v0.y; acc.z += v0.z; acc.w += v0.w;
            }
            float w = dinv[node];
            float4 r;
            r.x = fmaxf(fmaf(acc.x, w, bv.x), 0.f);
            r.y = fmaxf(fmaf(acc.y, w, bv.y), 0.f);
            r.z = fmaxf(fmaf(acc.z, w, bv.z), 0.f);
            r.w = fmaxf(fmaf(acc.w, w, bv.w), 0.f);
            *reinterpret_cast<float4*>(&act[(size_t)node * 64 + c0]) = r;
            s0 += r.x; s1 += r.y; s2 += r.z; s3 += r.w;
            q0 = fmaf(r.x, r.x, q0); q1 = fmaf(r.y, r.y, q1);
            q2 = fmaf(r.z, r.z, q2); q3 = fmaf(r.w, r.w, q3);
        }
    }

    __shared__ float ls[16 * 64];
    __shared__ float lq[16 * 64];
    *reinterpret_cast<float4*>(&ls[grp * 64 + c0]) = make_float4(s0, s1, s2, s3);
    *reinterpret_cast<float4*>(&lq[grp * 64 + c0]) = make_float4(q0, q1, q2, q3);
    __syncthreads();
    if (tid < 64) {
        float S = 0.f, Q = 0.f;
        #pragma unroll
        for (int g = 0; g < 16; ++g) { S += ls[g * 64 + tid]; Q += lq[g * 64 + tid]; }
        atomicAdd(&bn_sum[tid], S);
        atomicAdd(&bn_sq[tid],  Q);
    }
}

// ---------------------------------------------------------------- BN1 folded into W2
__global__ void k_bn_fold_w2(const float* __restrict__ bn_sum, const float* __restrict__ bn_sq,
                             const float* __restrict__ gamma, const float* __restrict__ beta,
                             const float* __restrict__ W2, float* __restrict__ W2eff,
                             float* __restrict__ c2, int n) {
    __shared__ float sc[64], sh[64];
    int t = threadIdx.x;
    float inv_n = 1.0f / (float)n;
    float mu  = bn_sum[t] * inv_n;
    float var = bn_sq[t] * inv_n - mu * mu;
    float s = gamma[t] * rsqrtf(var + 1e-5f);
    sc[t] = s; sh[t] = beta[t] - mu * s;
    __syncthreads();
    float acc = 0.f;
    for (int k = 0; k < 64; ++k) {
        float w = W2[k * 64 + t];
        W2eff[k * 64 + t] = sc[k] * w;
        acc = fmaf(sh[k], w, acc);
    }
    c2[t] = acc;
}

// ---------------------------------------------------------------- BN2 scale/shift
__global__ void k_bn_final(const float* __restrict__ bn_sum, const float* __restrict__ bn_sq,
                           const float* __restrict__ gamma, const float* __restrict__ beta,
                           float* __restrict__ scale, float* __restrict__ shift, int n) {
    int t = threadIdx.x;
    if (t >= 64) return;
    float inv_n = 1.0f / (float)n;
    float mu  = bn_sum[t] * inv_n;
    float var = bn_sq[t] * inv_n - mu * mu;
    float s = gamma[t] * rsqrtf(var + 1e-5f);
    scale[t] = s; shift[t] = beta[t] - mu * s;
}

// ---------------------------------------------------------------- pool + BN2 affine
__device__ __forceinline__ int lower_bound_i(const int* a, int n, int v) {
    int lo = 0, hi = n;
    while (lo < hi) { int m = (lo + hi) >> 1; if (a[m] < v) lo = m + 1; else hi = m; }
    return lo;
}
__global__ __launch_bounds__(256) void k_pool(const float* __restrict__ h, const int* __restrict__ batch,
                                              const float* __restrict__ scale, const float* __restrict__ shift,
                                              float* __restrict__ gp, int n) {
    int g = blockIdx.x;
    int lo = lower_bound_i(batch, n, g);
    int hi = lower_bound_i(batch, n, g + 1);
    int c  = threadIdx.x & 63;
    int rg = threadIdx.x >> 6;
    float s = 0.f;
    for (int r = lo + rg; r < hi; r += 4) s += h[r * 64 + c];
    __shared__ float ls[4][64];
    ls[rg][c] = s;
    __syncthreads();
    if (threadIdx.x < 64) {
        int cnt = hi - lo;
        float S = ls[0][c] + ls[1][c] + ls[2][c] + ls[3][c];
        float v = (cnt > 0) ? (S / (float)cnt) * scale[c] + shift[c] : 0.f;
        gp[g * 64 + c] = v;
    }
}

// ---------------------------------------------------------------- MLP head
__global__ __launch_bounds__(128) void k_mlp(const float* __restrict__ gp,
                                             const float* __restrict__ fW1, const float* __restrict__ fb1,
                                             const float* __restrict__ fW2, const float* __restrict__ fb2,
                                             const float* __restrict__ fW3, const float* __restrict__ fb3,
                                             const float* __restrict__ fW4, const float* __restrict__ fb4,
                                             const float* __restrict__ oW,  const float* __restrict__ ob,
                                             float* __restrict__ out) {
    int g = blockIdx.x;
    int t = threadIdx.x;
    __shared__ float a[128], bbuf[128];
    if (t < 64) a[t] = gp[g * 64 + t];
    __syncthreads();
    {
        float acc = fb1[t];
        for (int k = 0; k < 64; ++k) acc = fmaf(a[k], fW1[k * 128 + t], acc);
        bbuf[t] = fmaxf(acc, 0.f);
    }
    __syncthreads();
    if (t < 64) {
        float acc = fb2[t];
        for (int k = 0; k < 128; ++k) acc = fmaf(bbuf[k], fW2[k * 64 + t], acc);
        a[t] = fmaxf(acc, 0.f);
    }
    __syncthreads();
    if (t < 32) {
        float acc = fb3[t];
        for (int k = 0; k < 64; ++k) acc = fmaf(a[k], fW3[k * 32 + t], acc);
        bbuf[t] = fmaxf(acc, 0.f);
    }
    __syncthreads();
    if (t < 16) {
        float acc = fb4[t];
        for (int k = 0; k < 32; ++k) acc = fmaf(bbuf[k], fW4[k * 16 + t], acc);
        a[t] = fmaxf(acc, 0.f);
    }
    __syncthreads();
    if (t == 0) {
        float acc = ob[0];
        for (int k = 0; k < 16; ++k) acc = fmaf(a[k], oW[k], acc);
        out[g] = acc;
    }
}

// ---------------------------------------------------------------- launch
extern "C" void kernel_launch(void* const* d_in, const int* in_sizes, int n_in,
                              void* d_out, int out_size, void* d_ws, size_t ws_size,
                              hipStream_t stream) {
    const float* x      = (const float*)d_in[0];
    const int*   ei     = (const int*)  d_in[1];
    const int*   batch  = (const int*)  d_in[2];
    const float* W1     = (const float*)d_in[3];
    const float* b1     = (const float*)d_in[4];
    const float* W2     = (const float*)d_in[5];
    const float* b2     = (const float*)d_in[6];
    const float* gamma1 = (const float*)d_in[7];
    const float* beta1  = (const float*)d_in[8];
    const float* gamma2 = (const float*)d_in[9];
    const float* beta2  = (const float*)d_in[10];
    const float* fW1    = (const float*)d_in[11];
    const float* fb1    = (const float*)d_in[12];
    const float* fW2    = (const float*)d_in[13];
    const float* fb2    = (const float*)d_in[14];
    const float* fW3    = (const float*)d_in[15];
    const float* fb3    = (const float*)d_in[16];
    const float* fW4    = (const float*)d_in[17];
    const float* fb4    = (const float*)d_in[18];
    const float* oW     = (const float*)d_in[19];
    const float* ob     = (const float*)d_in[20];
    float* out = (float*)d_out;

    const int N = NNODES, E = NEDGES, G = NGRAPH;
    const int NB = (N + 255) / 256;   // 391 scan blocks

    // workspace layout
    float*    bufA   = (float*)d_ws;                       // N*64  (hd)
    float*    bufB   = bufA + (size_t)N * 64;              // N*64  (act)
    unsigned* indeg  = (unsigned*)(bufB + (size_t)N * 64); // N
    float*    dinv   = (float*)(indeg + N);                // N
    unsigned* rowptr = (unsigned*)(dinv + N);              // N+1
    unsigned* cursor = rowptr + (N + 1);                   // N
    unsigned* colidx = cursor + N;                         // E
    unsigned* bsum   = colidx + E;                         // 512
    unsigned* boff   = bsum + 512;                         // 512
    float*    bn1s   = (float*)(boff + 512);               // 64
    float*    bn1q   = bn1s + 64;                          // 64
    float*    bn2s   = bn1q + 64;                          // 64
    float*    bn2q   = bn2s + 64;                          // 64
    float*    scale2 = bn2q + 64;                          // 64
    float*    shift2 = scale2 + 64;                        // 64
    float*    W2eff  = shift2 + 64;                        // 4096
    float*    c2     = W2eff + 4096;                       // 64
    float*    gpool  = c2 + 64;                            // G*64

    // --- zero accumulators (async memset is graph-capture safe) ---
    hipMemsetAsync(indeg, 0, (size_t)N * 4, stream);
    hipMemsetAsync(bn1s, 0, 4 * 64 * sizeof(float), stream);   // bn1s,bn1q,bn2s,bn2q

    // --- degrees + CSR scan ---
    k_count_deg<<<(E + 255) / 256, 256, 0, stream>>>(ei, indeg, E);
    k_block_reduce<<<NB, 256, 0, stream>>>(indeg, bsum, N);
    k_scan_bsum<<<1, 512, 0, stream>>>(bsum, boff, NB);
    k_scan_final<<<NB, 256, 0, stream>>>(indeg, boff, rowptr, cursor, dinv, N);

    // --- fused: GEMM1 (hd1 = (x@W1)*dinv) overlapped with CSR fill ---
    k_gemm1_fill<<<7813, 256, 0, stream>>>(x, W1, dinv, bufA, ei, cursor, colidx);

    // --- layer 1 aggregate + bias + relu + BN1 stats ---
    k_gather_fused<<<(N + 127) / 128, 256, 0, stream>>>(rowptr, colidx, bufA, dinv, b1, bufB, bn1s, bn1q, N);
    k_bn_fold_w2<<<1, 64, 0, stream>>>(bn1s, bn1q, gamma1, beta1, W2, W2eff, c2, N);

    // --- layer 2: hd2 = (act1 @ W2eff + c2) * dinv ---
    k_gemm64<64><<<(N + 63) / 64, 256, 0, stream>>>(bufB, W2eff, c2, dinv, bufA, N);
    k_gather_fused<<<(N + 127) / 128, 256, 0, stream>>>(rowptr, colidx, bufA, dinv, b2, bufB, bn2s, bn2q, N);
    k_bn_final<<<1, 64, 0, stream>>>(bn2s, bn2q, gamma2, beta2, scale2, shift2, N);

    // --- pool + MLP ---
    k_pool<<<G, 256, 0, stream>>>(bufB, batch, scale2, shift2, gpool, N);
    k_mlp<<<G, 128, 0, stream>>>(gpool, fW1, fb1, fW2, fb2, fW3, fb3, fW4, fb4, oW, ob, out);
}

// Round 4
// 517.562 us; speedup vs baseline: 6.0655x; 1.1537x over previous
//
#include <hip/hip_runtime.h>
#include <hip/hip_bf16.h>

#define NNODES 100000
#define NEDGES 1600000
#define NGRAPH 64

// ---------------------------------------------------------------- degrees
__global__ void k_count_deg(const int* __restrict__ ei, unsigned* indeg, int E) {
    int e = blockIdx.x * 256 + threadIdx.x;
    if (e < E) atomicAdd(&indeg[ei[E + e]], 1u);   // dst side
}

// ---------------------------------------------------------------- CSR build: scan
__global__ __launch_bounds__(256) void k_block_reduce(const unsigned* __restrict__ v, unsigned* bsum, int n) {
    __shared__ unsigned s[256];
    int i = blockIdx.x * 256 + threadIdx.x;
    s[threadIdx.x] = (i < n) ? v[i] : 0u;
    __syncthreads();
    for (int off = 128; off > 0; off >>= 1) {
        if (threadIdx.x < off) s[threadIdx.x] += s[threadIdx.x + off];
        __syncthreads();
    }
    if (threadIdx.x == 0) bsum[blockIdx.x] = s[0];
}
__global__ __launch_bounds__(512) void k_scan_bsum(const unsigned* __restrict__ bsum, unsigned* boff, int nb) {
    __shared__ unsigned s[512];
    int t = threadIdx.x;
    unsigned mine = (t < nb) ? bsum[t] : 0u;
    s[t] = mine;
    __syncthreads();
    for (int off = 1; off < 512; off <<= 1) {
        unsigned u = (t >= off) ? s[t - off] : 0u;
        __syncthreads();
        s[t] += u;
        __syncthreads();
    }
    if (t < nb) boff[t] = s[t] - mine;   // exclusive
}
// final scan; also emits dinv = rsqrt(indeg+1) (self-loop)
__global__ __launch_bounds__(256) void k_scan_final(const unsigned* __restrict__ indeg,
                                                    const unsigned* __restrict__ boff,
                                                    unsigned* __restrict__ rowptr,
                                                    unsigned* __restrict__ cursor,
                                                    float* __restrict__ dinv, int n) {
    __shared__ unsigned s[256];
    int i = blockIdx.x * 256 + threadIdx.x;
    unsigned v = (i < n) ? indeg[i] : 0u;
    s[threadIdx.x] = v;
    __syncthreads();
    for (int off = 1; off < 256; off <<= 1) {
        unsigned u = (threadIdx.x >= off) ? s[threadIdx.x - off] : 0u;
        __syncthreads();
        s[threadIdx.x] += u;
        __syncthreads();
    }
    if (i < n) {
        unsigned ex = s[threadIdx.x] - v + boff[blockIdx.x];
        rowptr[i] = ex;
        cursor[i] = ex;
        dinv[i]   = rsqrtf((float)(v + 1u));
        if (i == n - 1) rowptr[n] = s[threadIdx.x] + boff[blockIdx.x];
    }
}

// ---------------------------------------------------------------- fused GEMM1 (x@W1 *dinv) + CSR fill
__global__ __launch_bounds__(256) void k_gemm1_fill(const float* __restrict__ A,
                                                    const float* __restrict__ W,
                                                    const float* __restrict__ rowscale,
                                                    float* __restrict__ out,
                                                    const int* __restrict__ ei,
                                                    unsigned* __restrict__ cursor,
                                                    unsigned* __restrict__ colidx) {
    __shared__ float wlds[64 * 64];
    __shared__ float alds[64 * 68];
    const int b = blockIdx.x;
    const int tid = threadIdx.x;

    if (b % 5 == 0) {
        const int row0 = (b / 5) * 64;
        const int tc = (tid & 15) * 4;
        const int tr = (tid >> 4) * 4;
        float acc[4][4];
        #pragma unroll
        for (int i = 0; i < 4; ++i)
            #pragma unroll
            for (int j = 0; j < 4; ++j) acc[i][j] = 0.f;

        for (int kc = 0; kc < 2; ++kc) {
            for (int idx = tid; idx < 64 * 16; idx += 256) {
                int r = idx >> 4, kk = (idx & 15) * 4;
                *reinterpret_cast<float4*>(&wlds[r * 64 + kk]) =
                    *reinterpret_cast<const float4*>(&W[(kc * 64 + r) * 64 + kk]);
            }
            for (int idx = tid; idx < 64 * 16; idx += 256) {
                int r = idx >> 4, kk = (idx & 15) * 4;
                int row = row0 + r;
                float4 v = make_float4(0.f, 0.f, 0.f, 0.f);
                if (row < NNODES) v = *reinterpret_cast<const float4*>(&A[row * 128 + kc * 64 + kk]);
                *reinterpret_cast<float4*>(&alds[r * 68 + kk]) = v;
            }
            __syncthreads();
            #pragma unroll 8
            for (int k = 0; k < 64; ++k) {
                float4 wv = *reinterpret_cast<const float4*>(&wlds[k * 64 + tc]);
                float av[4];
                #pragma unroll
                for (int i = 0; i < 4; ++i) av[i] = alds[(tr + i) * 68 + k];
                #pragma unroll
                for (int i = 0; i < 4; ++i) {
                    acc[i][0] = fmaf(av[i], wv.x, acc[i][0]);
                    acc[i][1] = fmaf(av[i], wv.y, acc[i][1]);
                    acc[i][2] = fmaf(av[i], wv.z, acc[i][2]);
                    acc[i][3] = fmaf(av[i], wv.w, acc[i][3]);
                }
            }
            __syncthreads();
        }
        #pragma unroll
        for (int i = 0; i < 4; ++i) {
            int row = row0 + tr + i;
            if (row < NNODES) {
                float f = rowscale[row];
                *reinterpret_cast<float4*>(&out[row * 64 + tc]) =
                    make_float4(acc[i][0]*f, acc[i][1]*f, acc[i][2]*f, acc[i][3]*f);
            }
        }
    } else {
        int fi = b - (b + 4) / 5;
        int e = fi * 256 + tid;
        if (e < NEDGES) {
            int src = ei[e], dst = ei[NEDGES + e];
            unsigned pos = atomicAdd(&cursor[dst], 1u);
            colidx[pos] = (unsigned)src;
        }
    }
}

// ---------------------------------------------------------------- standalone GEMM for layer 2
template <int K>
__global__ __launch_bounds__(256) void k_gemm64(const float* __restrict__ A,
                                                const float* __restrict__ W,
                                                const float* __restrict__ addvec,
                                                const float* __restrict__ rowscale,
                                                float* __restrict__ out, int n) {
    __shared__ float wlds[64 * 64];
    __shared__ float alds[64 * 68];
    const int tid = threadIdx.x;
    const int tc  = (tid & 15) * 4;
    const int tr  = (tid >> 4) * 4;
    const int row0 = blockIdx.x * 64;

    float acc[4][4];
    float4 cv = *reinterpret_cast<const float4*>(&addvec[tc]);
    #pragma unroll
    for (int i = 0; i < 4; ++i) { acc[i][0]=cv.x; acc[i][1]=cv.y; acc[i][2]=cv.z; acc[i][3]=cv.w; }

    for (int kc = 0; kc < K / 64; ++kc) {
        for (int idx = tid; idx < 64 * 16; idx += 256) {
            int r = idx >> 4, kk = (idx & 15) * 4;
            *reinterpret_cast<float4*>(&wlds[r * 64 + kk]) =
                *reinterpret_cast<const float4*>(&W[(kc * 64 + r) * 64 + kk]);
        }
        for (int idx = tid; idx < 64 * 16; idx += 256) {
            int r = idx >> 4, kk = (idx & 15) * 4;
            int row = row0 + r;
            float4 v = make_float4(0.f, 0.f, 0.f, 0.f);
            if (row < n) v = *reinterpret_cast<const float4*>(&A[row * K + kc * 64 + kk]);
            *reinterpret_cast<float4*>(&alds[r * 68 + kk]) = v;
        }
        __syncthreads();
        #pragma unroll 8
        for (int k = 0; k < 64; ++k) {
            float4 wv = *reinterpret_cast<const float4*>(&wlds[k * 64 + tc]);
            float av[4];
            #pragma unroll
            for (int i = 0; i < 4; ++i) av[i] = alds[(tr + i) * 68 + k];
            #pragma unroll
            for (int i = 0; i < 4; ++i) {
                acc[i][0] = fmaf(av[i], wv.x, acc[i][0]);
                acc[i][1] = fmaf(av[i], wv.y, acc[i][1]);
                acc[i][2] = fmaf(av[i], wv.z, acc[i][2]);
                acc[i][3] = fmaf(av[i], wv.w, acc[i][3]);
            }
        }
        __syncthreads();
    }
    #pragma unroll
    for (int i = 0; i < 4; ++i) {
        int row = row0 + tr + i;
        if (row < n) {
            float f = rowscale[row];
            *reinterpret_cast<float4*>(&out[row * 64 + tc]) =
                make_float4(acc[i][0]*f, acc[i][1]*f, acc[i][2]*f, acc[i][3]*f);
        }
    }
}

// ---------------------------------------------------------------- fused gather + bias + relu + BN stats
__global__ __launch_bounds__(256) void k_gather_fused(const unsigned* __restrict__ rowptr,
                                                      const unsigned* __restrict__ colidx,
                                                      const float* __restrict__ hd,
                                                      const float* __restrict__ dinv,
                                                      const float* __restrict__ bias,
                                                      float* __restrict__ act,
                                                      float* bn_sum, float* bn_sq, int n) {
    const int tid   = threadIdx.x;
    const int grp   = tid >> 4;          // 0..15
    const int c0    = (tid & 15) * 4;
    float4 bv = *reinterpret_cast<const float4*>(&bias[c0]);
    float s0=0.f,s1=0.f,s2=0.f,s3=0.f, q0=0.f,q1=0.f,q2=0.f,q3=0.f;

    #pragma unroll
    for (int it = 0; it < 8; ++it) {
        int node = (blockIdx.x * 8 + it) * 16 + grp;
        if (node < n) {
            unsigned lo = rowptr[node], hi = rowptr[node + 1];
            float4 acc = *reinterpret_cast<const float4*>(&hd[(size_t)node * 64 + c0]);
            unsigned j = lo;
            for (; j + 4 <= hi; j += 4) {
                unsigned a0 = colidx[j], a1 = colidx[j+1], a2 = colidx[j+2], a3 = colidx[j+3];
                float4 v0 = *reinterpret_cast<const float4*>(&hd[(size_t)a0 * 64 + c0]);
                float4 v1 = *reinterpret_cast<const float4*>(&hd[(size_t)a1 * 64 + c0]);
                float4 v2 = *reinterpret_cast<const float4*>(&hd[(size_t)a2 * 64 + c0]);
                float4 v3 = *reinterpret_cast<const float4*>(&hd[(size_t)a3 * 64 + c0]);
                acc.x += (v0.x + v1.x) + (v2.x + v3.x);
                acc.y += (v0.y + v1.y) + (v2.y + v3.y);
                acc.z += (v0.z + v1.z) + (v2.z + v3.z);
                acc.w += (v0.w + v1.w) + (v2.w + v3.w);
            }
            for (; j < hi; ++j) {
                unsigned a0 = colidx[j];
                float4 v0 = *reinterpret_cast<const float4*>(&hd[(size_t)a0 * 64 + c0]);
                acc.x += v0.x; acc.y += v0.y; acc.z += v0.z; acc.w += v0.w;
            }
            float w = dinv[node];
            float4 r;
            r.x = fmaxf(fmaf(acc.x, w, bv.x), 0.f);
            r.y = fmaxf(fmaf(acc.y, w, bv.y), 0.f);
            r.z = fmaxf(fmaf(acc.z, w, bv.z), 0.f);
            r.w = fmaxf(fmaf(acc.w, w, bv.w), 0.f);
            *reinterpret_cast<float4*>(&act[(size_t)node * 64 + c0]) = r;
            s0 += r.x; s1 += r.y; s2 += r.z; s3 += r.w;
            q0 = fmaf(r.x, r.x, q0); q1 = fmaf(r.y, r.y, q1);
            q2 = fmaf(r.z, r.z, q2); q3 = fmaf(r.w, r.w, q3);
        }
    }

    __shared__ float ls[16 * 64];
    __shared__ float lq[16 * 64];
    *reinterpret_cast<float4*>(&ls[grp * 64 + c0]) = make_float4(s0, s1, s2, s3);
    *reinterpret_cast<float4*>(&lq[grp * 64 + c0]) = make_float4(q0, q1, q2, q3);
    __syncthreads();
    if (tid < 64) {
        float S = 0.f, Q = 0.f;
        #pragma unroll
        for (int g = 0; g < 16; ++g) { S += ls[g * 64 + tid]; Q += lq[g * 64 + tid]; }
        atomicAdd(&bn_sum[tid], S);
        atomicAdd(&bn_sq[tid],  Q);
    }
}

// ---------------------------------------------------------------- BN1 folded into W2
__global__ void k_bn_fold_w2(const float* __restrict__ bn_sum, const float* __restrict__ bn_sq,
                             const float* __restrict__ gamma, const float* __restrict__ beta,
                             const float* __restrict__ W2, float* __restrict__ W2eff,
                             float* __restrict__ c2, int n) {
    __shared__ float sc[64], sh[64];
    int t = threadIdx.x;
    float inv_n = 1.0f / (float)n;
    float mu  = bn_sum[t] * inv_n;
    float var = bn_sq[t] * inv_n - mu * mu;
    float s = gamma[t] * rsqrtf(var + 1e-5f);
    sc[t] = s; sh[t] = beta[t] - mu * s;
    __syncthreads();
    float acc = 0.f;
    for (int k = 0; k < 64; ++k) {
        float w = W2[k * 64 + t];
        W2eff[k * 64 + t] = sc[k] * w;
        acc = fmaf(sh[k], w, acc);
    }
    c2[t] = acc;
}

// ---------------------------------------------------------------- BN2 scale/shift
__global__ void k_bn_final(const float* __restrict__ bn_sum, const float* __restrict__ bn_sq,
                           const float* __restrict__ gamma, const float* __restrict__ beta,
                           float* __restrict__ scale, float* __restrict__ shift, int n) {
    int t = threadIdx.x;
    if (t >= 64) return;
    float inv_n = 1.0f / (float)n;
    float mu  = bn_sum[t] * inv_n;
    float var = bn_sq[t] * inv_n - mu * mu;
    float s = gamma[t] * rsqrtf(var + 1e-5f);
    scale[t] = s; shift[t] = beta[t] - mu * s;
}

// ---------------------------------------------------------------- pool partial: run-length + atomic flush
// block covers 128 contiguous rows; batch sorted => <=~2 flushes per thread.
__global__ __launch_bounds__(256) void k_pool_partial(const float* __restrict__ h,
                                                      const int* __restrict__ batch,
                                                      float* __restrict__ gsum, int n) {
    int c  = threadIdx.x & 63;
    int rg = threadIdx.x >> 6;
    int row0 = blockIdx.x * 128;
    int gcur = -1;
    float acc = 0.f;
    for (int i = 0; i < 32; ++i) {
        int r = row0 + rg + i * 4;
        if (r < n) {
            int g = batch[r];                   // wave-uniform scalar load
            if (g != gcur) {
                if (gcur >= 0) atomicAdd(&gsum[gcur * 64 + c], acc);
                gcur = g; acc = 0.f;
            }
            acc += h[(size_t)r * 64 + c];
        }
    }
    if (gcur >= 0) atomicAdd(&gsum[gcur * 64 + c], acc);
}

// ---------------------------------------------------------------- MLP head (+ pool finalize & BN2 affine)
__device__ __forceinline__ int lower_bound_i(const int* a, int n, int v) {
    int lo = 0, hi = n;
    while (lo < hi) { int m = (lo + hi) >> 1; if (a[m] < v) lo = m + 1; else hi = m; }
    return lo;
}
__global__ __launch_bounds__(128) void k_mlp(const float* __restrict__ gsum,
                                             const int* __restrict__ batch, int n,
                                             const float* __restrict__ scale, const float* __restrict__ shift,
                                             const float* __restrict__ fW1, const float* __restrict__ fb1,
                                             const float* __restrict__ fW2, const float* __restrict__ fb2,
                                             const float* __restrict__ fW3, const float* __restrict__ fb3,
                                             const float* __restrict__ fW4, const float* __restrict__ fb4,
                                             const float* __restrict__ oW,  const float* __restrict__ ob,
                                             float* __restrict__ out) {
    int g = blockIdx.x;
    int t = threadIdx.x;
    __shared__ float a[128], bbuf[128];
    if (t < 64) {
        int lo = lower_bound_i(batch, n, g);
        int hi = lower_bound_i(batch, n, g + 1);
        int cnt = hi - lo;
        a[t] = (cnt > 0) ? (gsum[g * 64 + t] / (float)cnt) * scale[t] + shift[t] : 0.f;
    }
    __syncthreads();
    {
        float acc = fb1[t];
        for (int k = 0; k < 64; ++k) acc = fmaf(a[k], fW1[k * 128 + t], acc);
        bbuf[t] = fmaxf(acc, 0.f);
    }
    __syncthreads();
    if (t < 64) {
        float acc = fb2[t];
        for (int k = 0; k < 128; ++k) acc = fmaf(bbuf[k], fW2[k * 64 + t], acc);
        a[t] = fmaxf(acc, 0.f);
    }
    __syncthreads();
    if (t < 32) {
        float acc = fb3[t];
        for (int k = 0; k < 64; ++k) acc = fmaf(a[k], fW3[k * 32 + t], acc);
        bbuf[t] = fmaxf(acc, 0.f);
    }
    __syncthreads();
    if (t < 16) {
        float acc = fb4[t];
        for (int k = 0; k < 32; ++k) acc = fmaf(bbuf[k], fW4[k * 16 + t], acc);
        a[t] = fmaxf(acc, 0.f);
    }
    __syncthreads();
    if (t == 0) {
        float acc = ob[0];
        for (int k = 0; k < 16; ++k) acc = fmaf(a[k], oW[k], acc);
        out[g] = acc;
    }
}

// ---------------------------------------------------------------- launch
extern "C" void kernel_launch(void* const* d_in, const int* in_sizes, int n_in,
                              void* d_out, int out_size, void* d_ws, size_t ws_size,
                              hipStream_t stream) {
    const float* x      = (const float*)d_in[0];
    const int*   ei     = (const int*)  d_in[1];
    const int*   batch  = (const int*)  d_in[2];
    const float* W1     = (const float*)d_in[3];
    const float* b1     = (const float*)d_in[4];
    const float* W2     = (const float*)d_in[5];
    const float* b2     = (const float*)d_in[6];
    const float* gamma1 = (const float*)d_in[7];
    const float* beta1  = (const float*)d_in[8];
    const float* gamma2 = (const float*)d_in[9];
    const float* beta2  = (const float*)d_in[10];
    const float* fW1    = (const float*)d_in[11];
    const float* fb1    = (const float*)d_in[12];
    const float* fW2    = (const float*)d_in[13];
    const float* fb2    = (const float*)d_in[14];
    const float* fW3    = (const float*)d_in[15];
    const float* fb3    = (const float*)d_in[16];
    const float* fW4    = (const float*)d_in[17];
    const float* fb4    = (const float*)d_in[18];
    const float* oW     = (const float*)d_in[19];
    const float* ob     = (const float*)d_in[20];
    float* out = (float*)d_out;

    const int N = NNODES, E = NEDGES, G = NGRAPH;
    const int NB = (N + 255) / 256;

    // workspace layout
    float*    bufA   = (float*)d_ws;                       // N*64  (hd)
    float*    bufB   = bufA + (size_t)N * 64;              // N*64  (act)
    unsigned* indeg  = (unsigned*)(bufB + (size_t)N * 64); // N
    float*    dinv   = (float*)(indeg + N);                // N
    unsigned* rowptr = (unsigned*)(dinv + N);              // N+1
    unsigned* cursor = rowptr + (N + 1);                   // N
    unsigned* colidx = cursor + N;                         // E
    unsigned* bsum   = colidx + E;                         // 512
    unsigned* boff   = bsum + 512;                         // 512
    float*    bn1s   = (float*)(boff + 512);               // 64
    float*    bn1q   = bn1s + 64;                          // 64
    float*    bn2s   = bn1q + 64;                          // 64
    float*    bn2q   = bn2s + 64;                          // 64
    float*    scale2 = bn2q + 64;                          // 64
    float*    shift2 = scale2 + 64;                        // 64
    float*    W2eff  = shift2 + 64;                        // 4096
    float*    c2     = W2eff + 4096;                       // 64
    float*    gsum   = c2 + 64;                            // G*64

    // --- zero accumulators ---
    hipMemsetAsync(indeg, 0, (size_t)N * 4, stream);
    hipMemsetAsync(bn1s, 0, 4 * 64 * sizeof(float), stream);
    hipMemsetAsync(gsum, 0, (size_t)G * 64 * sizeof(float), stream);

    // --- degrees + CSR scan ---
    k_count_deg<<<(E + 255) / 256, 256, 0, stream>>>(ei, indeg, E);
    k_block_reduce<<<NB, 256, 0, stream>>>(indeg, bsum, N);
    k_scan_bsum<<<1, 512, 0, stream>>>(bsum, boff, NB);
    k_scan_final<<<NB, 256, 0, stream>>>(indeg, boff, rowptr, cursor, dinv, N);

    // --- fused: GEMM1 (hd1 = (x@W1)*dinv) overlapped with CSR fill ---
    k_gemm1_fill<<<7813, 256, 0, stream>>>(x, W1, dinv, bufA, ei, cursor, colidx);

    // --- layer 1 aggregate + bias + relu + BN1 stats ---
    k_gather_fused<<<(N + 127) / 128, 256, 0, stream>>>(rowptr, colidx, bufA, dinv, b1, bufB, bn1s, bn1q, N);
    k_bn_fold_w2<<<1, 64, 0, stream>>>(bn1s, bn1q, gamma1, beta1, W2, W2eff, c2, N);

    // --- layer 2 ---
    k_gemm64<64><<<(N + 63) / 64, 256, 0, stream>>>(bufB, W2eff, c2, dinv, bufA, N);
    k_gather_fused<<<(N + 127) / 128, 256, 0, stream>>>(rowptr, colidx, bufA, dinv, b2, bufB, bn2s, bn2q, N);
    k_bn_final<<<1, 64, 0, stream>>>(bn2s, bn2q, gamma2, beta2, scale2, shift2, N);

    // --- pool (two-phase) + MLP (finalize fused) ---
    k_pool_partial<<<(N + 127) / 128, 256, 0, stream>>>(bufB, batch, gsum, N);
    k_mlp<<<G, 128, 0, stream>>>(gsum, batch, N, scale2, shift2,
                                 fW1, fb1, fW2, fb2, fW3, fb3, fW4, fb4, oW, ob, out);
}

// Round 5
// 495.847 us; speedup vs baseline: 6.3311x; 1.0438x over previous
//
#include <hip/hip_runtime.h>
#include <hip/hip_bf16.h>
#include <hip/hip_fp16.h>

#define NNODES 100000
#define NEDGES 1600000
#define NGRAPH 64

// ---------------------------------------------------------------- degrees (4 edges/thread)
__global__ void k_count_deg(const int* __restrict__ ei, unsigned* indeg, int E) {
    int e4 = blockIdx.x * 256 + threadIdx.x;
    if (e4 * 4 < E) {
        int4 d = *reinterpret_cast<const int4*>(&ei[E + e4 * 4]);
        atomicAdd(&indeg[d.x], 1u);
        atomicAdd(&indeg[d.y], 1u);
        atomicAdd(&indeg[d.z], 1u);
        atomicAdd(&indeg[d.w], 1u);
    }
}

// ---------------------------------------------------------------- CSR build: scan
__global__ __launch_bounds__(256) void k_block_reduce(const unsigned* __restrict__ v, unsigned* bsum, int n) {
    __shared__ unsigned s[256];
    int i = blockIdx.x * 256 + threadIdx.x;
    s[threadIdx.x] = (i < n) ? v[i] : 0u;
    __syncthreads();
    for (int off = 128; off > 0; off >>= 1) {
        if (threadIdx.x < off) s[threadIdx.x] += s[threadIdx.x + off];
        __syncthreads();
    }
    if (threadIdx.x == 0) bsum[blockIdx.x] = s[0];
}
__global__ __launch_bounds__(512) void k_scan_bsum(const unsigned* __restrict__ bsum, unsigned* boff, int nb) {
    __shared__ unsigned s[512];
    int t = threadIdx.x;
    unsigned mine = (t < nb) ? bsum[t] : 0u;
    s[t] = mine;
    __syncthreads();
    for (int off = 1; off < 512; off <<= 1) {
        unsigned u = (t >= off) ? s[t - off] : 0u;
        __syncthreads();
        s[t] += u;
        __syncthreads();
    }
    if (t < nb) boff[t] = s[t] - mine;   // exclusive
}
__global__ __launch_bounds__(256) void k_scan_final(const unsigned* __restrict__ indeg,
                                                    const unsigned* __restrict__ boff,
                                                    unsigned* __restrict__ rowptr,
                                                    unsigned* __restrict__ cursor,
                                                    float* __restrict__ dinv, int n) {
    __shared__ unsigned s[256];
    int i = blockIdx.x * 256 + threadIdx.x;
    unsigned v = (i < n) ? indeg[i] : 0u;
    s[threadIdx.x] = v;
    __syncthreads();
    for (int off = 1; off < 256; off <<= 1) {
        unsigned u = (threadIdx.x >= off) ? s[threadIdx.x - off] : 0u;
        __syncthreads();
        s[threadIdx.x] += u;
        __syncthreads();
    }
    if (i < n) {
        unsigned ex = s[threadIdx.x] - v + boff[blockIdx.x];
        rowptr[i] = ex;
        cursor[i] = ex;
        dinv[i]   = rsqrtf((float)(v + 1u));
        if (i == n - 1) rowptr[n] = s[threadIdx.x] + boff[blockIdx.x];
    }
}

// ---------------------------------------------------------------- fused GEMM1 (x@W1 *dinv -> fp16) + CSR fill
__global__ __launch_bounds__(256) void k_gemm1_fill(const float* __restrict__ A,
                                                    const float* __restrict__ W,
                                                    const float* __restrict__ rowscale,
                                                    __half* __restrict__ hd,
                                                    const int* __restrict__ ei,
                                                    unsigned* __restrict__ cursor,
                                                    unsigned* __restrict__ colidx) {
    __shared__ float wlds[64 * 64];
    __shared__ float alds[64 * 68];
    const int b = blockIdx.x;
    const int tid = threadIdx.x;

    if (b % 5 == 0) {
        const int row0 = (b / 5) * 64;
        const int tc = (tid & 15) * 4;
        const int tr = (tid >> 4) * 4;
        float acc[4][4];
        #pragma unroll
        for (int i = 0; i < 4; ++i)
            #pragma unroll
            for (int j = 0; j < 4; ++j) acc[i][j] = 0.f;

        for (int kc = 0; kc < 2; ++kc) {
            for (int idx = tid; idx < 64 * 16; idx += 256) {
                int r = idx >> 4, kk = (idx & 15) * 4;
                *reinterpret_cast<float4*>(&wlds[r * 64 + kk]) =
                    *reinterpret_cast<const float4*>(&W[(kc * 64 + r) * 64 + kk]);
            }
            for (int idx = tid; idx < 64 * 16; idx += 256) {
                int r = idx >> 4, kk = (idx & 15) * 4;
                int row = row0 + r;
                float4 v = make_float4(0.f, 0.f, 0.f, 0.f);
                if (row < NNODES) v = *reinterpret_cast<const float4*>(&A[row * 128 + kc * 64 + kk]);
                *reinterpret_cast<float4*>(&alds[r * 68 + kk]) = v;
            }
            __syncthreads();
            #pragma unroll 8
            for (int k = 0; k < 64; ++k) {
                float4 wv = *reinterpret_cast<const float4*>(&wlds[k * 64 + tc]);
                float av[4];
                #pragma unroll
                for (int i = 0; i < 4; ++i) av[i] = alds[(tr + i) * 68 + k];
                #pragma unroll
                for (int i = 0; i < 4; ++i) {
                    acc[i][0] = fmaf(av[i], wv.x, acc[i][0]);
                    acc[i][1] = fmaf(av[i], wv.y, acc[i][1]);
                    acc[i][2] = fmaf(av[i], wv.z, acc[i][2]);
                    acc[i][3] = fmaf(av[i], wv.w, acc[i][3]);
                }
            }
            __syncthreads();
        }
        #pragma unroll
        for (int i = 0; i < 4; ++i) {
            int row = row0 + tr + i;
            if (row < NNODES) {
                float f = rowscale[row];
                __half2* p = reinterpret_cast<__half2*>(&hd[(size_t)row * 64 + tc]);
                p[0] = __floats2half2_rn(acc[i][0] * f, acc[i][1] * f);
                p[1] = __floats2half2_rn(acc[i][2] * f, acc[i][3] * f);
            }
        }
    } else {
        int fi = b - (b + 4) / 5;
        int e = fi * 256 + tid;
        if (e < NEDGES) {
            int src = ei[e], dst = ei[NEDGES + e];
            unsigned pos = atomicAdd(&cursor[dst], 1u);
            colidx[pos] = (unsigned)src;
        }
    }
}

// ---------------------------------------------------------------- GEMM (layer2): act1 @ W2eff + c2, *dinv -> fp16
__global__ __launch_bounds__(256) void k_gemm64_h(const float* __restrict__ A,
                                                  const float* __restrict__ W,
                                                  const float* __restrict__ addvec,
                                                  const float* __restrict__ rowscale,
                                                  __half* __restrict__ hd, int n) {
    __shared__ float wlds[64 * 64];
    __shared__ float alds[64 * 68];
    const int tid = threadIdx.x;
    const int tc  = (tid & 15) * 4;
    const int tr  = (tid >> 4) * 4;
    const int row0 = blockIdx.x * 64;

    float acc[4][4];
    float4 cv = *reinterpret_cast<const float4*>(&addvec[tc]);
    #pragma unroll
    for (int i = 0; i < 4; ++i) { acc[i][0]=cv.x; acc[i][1]=cv.y; acc[i][2]=cv.z; acc[i][3]=cv.w; }

    {
        for (int idx = tid; idx < 64 * 16; idx += 256) {
            int r = idx >> 4, kk = (idx & 15) * 4;
            *reinterpret_cast<float4*>(&wlds[r * 64 + kk]) =
                *reinterpret_cast<const float4*>(&W[r * 64 + kk]);
        }
        for (int idx = tid; idx < 64 * 16; idx += 256) {
            int r = idx >> 4, kk = (idx & 15) * 4;
            int row = row0 + r;
            float4 v = make_float4(0.f, 0.f, 0.f, 0.f);
            if (row < n) v = *reinterpret_cast<const float4*>(&A[row * 64 + kk]);
            *reinterpret_cast<float4*>(&alds[r * 68 + kk]) = v;
        }
        __syncthreads();
        #pragma unroll 8
        for (int k = 0; k < 64; ++k) {
            float4 wv = *reinterpret_cast<const float4*>(&wlds[k * 64 + tc]);
            float av[4];
            #pragma unroll
            for (int i = 0; i < 4; ++i) av[i] = alds[(tr + i) * 68 + k];
            #pragma unroll
            for (int i = 0; i < 4; ++i) {
                acc[i][0] = fmaf(av[i], wv.x, acc[i][0]);
                acc[i][1] = fmaf(av[i], wv.y, acc[i][1]);
                acc[i][2] = fmaf(av[i], wv.z, acc[i][2]);
                acc[i][3] = fmaf(av[i], wv.w, acc[i][3]);
            }
        }
    }
    #pragma unroll
    for (int i = 0; i < 4; ++i) {
        int row = row0 + tr + i;
        if (row < n) {
            float f = rowscale[row];
            __half2* p = reinterpret_cast<__half2*>(&hd[(size_t)row * 64 + tc]);
            p[0] = __floats2half2_rn(acc[i][0] * f, acc[i][1] * f);
            p[1] = __floats2half2_rn(acc[i][2] * f, acc[i][3] * f);
        }
    }
}

// helper: accumulate one fp16 row segment (4 channels, 8 B) into float4
__device__ __forceinline__ void acc_row(const __half* __restrict__ hd, unsigned src, int c0, float4& acc) {
    uint2 u = *reinterpret_cast<const uint2*>(&hd[(size_t)src * 64 + c0]);
    __half2 x01 = *reinterpret_cast<__half2*>(&u.x);
    __half2 x23 = *reinterpret_cast<__half2*>(&u.y);
    float2 f01 = __half22float2(x01);
    float2 f23 = __half22float2(x23);
    acc.x += f01.x; acc.y += f01.y; acc.z += f23.x; acc.w += f23.y;
}

// ---------------------------------------------------------------- gather1: act = relu(dinv*(hd[d]+sum hd[src])+b), + BN stats
__global__ __launch_bounds__(256) void k_gather_fused(const unsigned* __restrict__ rowptr,
                                                      const unsigned* __restrict__ colidx,
                                                      const __half* __restrict__ hd,
                                                      const float* __restrict__ dinv,
                                                      const float* __restrict__ bias,
                                                      float* __restrict__ act,
                                                      float* bn_sum, float* bn_sq, int n) {
    const int tid = threadIdx.x;
    const int grp = tid >> 4;            // 0..15, each group = one node at a time
    const int c0  = (tid & 15) * 4;      // channel group
    float4 bv = *reinterpret_cast<const float4*>(&bias[c0]);
    float s0=0.f,s1=0.f,s2=0.f,s3=0.f, q0=0.f,q1=0.f,q2=0.f,q3=0.f;

    #pragma unroll
    for (int it = 0; it < 8; ++it) {
        int node = blockIdx.x * 128 + grp * 8 + it;
        if (node < n) {
            unsigned lo = rowptr[node], hi = rowptr[node + 1];
            float4 acc = make_float4(0.f, 0.f, 0.f, 0.f);
            acc_row(hd, (unsigned)node, c0, acc);
            unsigned j = lo;
            for (; j + 4 <= hi; j += 4) {
                unsigned a0 = colidx[j], a1 = colidx[j+1], a2 = colidx[j+2], a3 = colidx[j+3];
                acc_row(hd, a0, c0, acc);
                acc_row(hd, a1, c0, acc);
                acc_row(hd, a2, c0, acc);
                acc_row(hd, a3, c0, acc);
            }
            for (; j < hi; ++j) acc_row(hd, colidx[j], c0, acc);
            float w = dinv[node];
            float4 r;
            r.x = fmaxf(fmaf(acc.x, w, bv.x), 0.f);
            r.y = fmaxf(fmaf(acc.y, w, bv.y), 0.f);
            r.z = fmaxf(fmaf(acc.z, w, bv.z), 0.f);
            r.w = fmaxf(fmaf(acc.w, w, bv.w), 0.f);
            *reinterpret_cast<float4*>(&act[(size_t)node * 64 + c0]) = r;
            s0 += r.x; s1 += r.y; s2 += r.z; s3 += r.w;
            q0 = fmaf(r.x, r.x, q0); q1 = fmaf(r.y, r.y, q1);
            q2 = fmaf(r.z, r.z, q2); q3 = fmaf(r.w, r.w, q3);
        }
    }

    __shared__ float ls[16 * 64];
    __shared__ float lq[16 * 64];
    *reinterpret_cast<float4*>(&ls[grp * 64 + c0]) = make_float4(s0, s1, s2, s3);
    *reinterpret_cast<float4*>(&lq[grp * 64 + c0]) = make_float4(q0, q1, q2, q3);
    __syncthreads();
    if (tid < 64) {
        float S = 0.f, Q = 0.f;
        #pragma unroll
        for (int g = 0; g < 16; ++g) { S += ls[g * 64 + tid]; Q += lq[g * 64 + tid]; }
        atomicAdd(&bn_sum[tid], S);
        atomicAdd(&bn_sq[tid],  Q);
    }
}

// ---------------------------------------------------------------- gather2 + pool: no act materialization
// act2 = relu(...); per-graph run-length sums -> gsum (atomics); BN2 stats.
__global__ __launch_bounds__(256) void k_gather_pool(const unsigned* __restrict__ rowptr,
                                                     const unsigned* __restrict__ colidx,
                                                     const __half* __restrict__ hd,
                                                     const float* __restrict__ dinv,
                                                     const float* __restrict__ bias,
                                                     const int* __restrict__ batch,
                                                     float* __restrict__ gsum,
                                                     float* bn_sum, float* bn_sq, int n) {
    const int tid = threadIdx.x;
    const int grp = tid >> 4;
    const int c0  = (tid & 15) * 4;
    float4 bv = *reinterpret_cast<const float4*>(&bias[c0]);
    float s0=0.f,s1=0.f,s2=0.f,s3=0.f, q0=0.f,q1=0.f,q2=0.f,q3=0.f;
    int gcur = -1;
    float4 pacc = make_float4(0.f, 0.f, 0.f, 0.f);

    #pragma unroll
    for (int it = 0; it < 8; ++it) {
        int node = blockIdx.x * 128 + grp * 8 + it;
        if (node < n) {
            unsigned lo = rowptr[node], hi = rowptr[node + 1];
            float4 acc = make_float4(0.f, 0.f, 0.f, 0.f);
            acc_row(hd, (unsigned)node, c0, acc);
            unsigned j = lo;
            for (; j + 4 <= hi; j += 4) {
                unsigned a0 = colidx[j], a1 = colidx[j+1], a2 = colidx[j+2], a3 = colidx[j+3];
                acc_row(hd, a0, c0, acc);
                acc_row(hd, a1, c0, acc);
                acc_row(hd, a2, c0, acc);
                acc_row(hd, a3, c0, acc);
            }
            for (; j < hi; ++j) acc_row(hd, colidx[j], c0, acc);
            float w = dinv[node];
            float4 r;
            r.x = fmaxf(fmaf(acc.x, w, bv.x), 0.f);
            r.y = fmaxf(fmaf(acc.y, w, bv.y), 0.f);
            r.z = fmaxf(fmaf(acc.z, w, bv.z), 0.f);
            r.w = fmaxf(fmaf(acc.w, w, bv.w), 0.f);
            s0 += r.x; s1 += r.y; s2 += r.z; s3 += r.w;
            q0 = fmaf(r.x, r.x, q0); q1 = fmaf(r.y, r.y, q1);
            q2 = fmaf(r.z, r.z, q2); q3 = fmaf(r.w, r.w, q3);
            // run-length pool (batch sorted, nodes contiguous per thread-group)
            int g = batch[node];
            if (g != gcur) {
                if (gcur >= 0) {
                    atomicAdd(&gsum[gcur * 64 + c0 + 0], pacc.x);
                    atomicAdd(&gsum[gcur * 64 + c0 + 1], pacc.y);
                    atomicAdd(&gsum[gcur * 64 + c0 + 2], pacc.z);
                    atomicAdd(&gsum[gcur * 64 + c0 + 3], pacc.w);
                }
                gcur = g;
                pacc = make_float4(0.f, 0.f, 0.f, 0.f);
            }
            pacc.x += r.x; pacc.y += r.y; pacc.z += r.z; pacc.w += r.w;
        }
    }
    if (gcur >= 0) {
        atomicAdd(&gsum[gcur * 64 + c0 + 0], pacc.x);
        atomicAdd(&gsum[gcur * 64 + c0 + 1], pacc.y);
        atomicAdd(&gsum[gcur * 64 + c0 + 2], pacc.z);
        atomicAdd(&gsum[gcur * 64 + c0 + 3], pacc.w);
    }

    __shared__ float ls[16 * 64];
    __shared__ float lq[16 * 64];
    *reinterpret_cast<float4*>(&ls[grp * 64 + c0]) = make_float4(s0, s1, s2, s3);
    *reinterpret_cast<float4*>(&lq[grp * 64 + c0]) = make_float4(q0, q1, q2, q3);
    __syncthreads();
    if (tid < 64) {
        float S = 0.f, Q = 0.f;
        #pragma unroll
        for (int g = 0; g < 16; ++g) { S += ls[g * 64 + tid]; Q += lq[g * 64 + tid]; }
        atomicAdd(&bn_sum[tid], S);
        atomicAdd(&bn_sq[tid],  Q);
    }
}

// ---------------------------------------------------------------- BN1 folded into W2
__global__ void k_bn_fold_w2(const float* __restrict__ bn_sum, const float* __restrict__ bn_sq,
                             const float* __restrict__ gamma, const float* __restrict__ beta,
                             const float* __restrict__ W2, float* __restrict__ W2eff,
                             float* __restrict__ c2, int n) {
    __shared__ float sc[64], sh[64];
    int t = threadIdx.x;
    float inv_n = 1.0f / (float)n;
    float mu  = bn_sum[t] * inv_n;
    float var = bn_sq[t] * inv_n - mu * mu;
    float s = gamma[t] * rsqrtf(var + 1e-5f);
    sc[t] = s; sh[t] = beta[t] - mu * s;
    __syncthreads();
    float acc = 0.f;
    for (int k = 0; k < 64; ++k) {
        float w = W2[k * 64 + t];
        W2eff[k * 64 + t] = sc[k] * w;
        acc = fmaf(sh[k], w, acc);
    }
    c2[t] = acc;
}

// ---------------------------------------------------------------- MLP head (+ BN2 finalize + pool finalize)
__device__ __forceinline__ int lower_bound_i(const int* a, int n, int v) {
    int lo = 0, hi = n;
    while (lo < hi) { int m = (lo + hi) >> 1; if (a[m] < v) lo = m + 1; else hi = m; }
    return lo;
}
__global__ __launch_bounds__(128) void k_mlp(const float* __restrict__ gsum,
                                             const int* __restrict__ batch, int n,
                                             const float* __restrict__ bn_sum, const float* __restrict__ bn_sq,
                                             const float* __restrict__ gamma, const float* __restrict__ beta,
                                             const float* __restrict__ fW1, const float* __restrict__ fb1,
                                             const float* __restrict__ fW2, const float* __restrict__ fb2,
                                             const float* __restrict__ fW3, const float* __restrict__ fb3,
                                             const float* __restrict__ fW4, const float* __restrict__ fb4,
                                             const float* __restrict__ oW,  const float* __restrict__ ob,
                                             float* __restrict__ out) {
    int g = blockIdx.x;
    int t = threadIdx.x;
    __shared__ float a[128], bbuf[128];
    if (t < 64) {
        float inv_n = 1.0f / (float)n;
        float mu  = bn_sum[t] * inv_n;
        float var = bn_sq[t] * inv_n - mu * mu;
        float s   = gamma[t] * rsqrtf(var + 1e-5f);
        float sh  = beta[t] - mu * s;
        int lo = lower_bound_i(batch, n, g);
        int hi = lower_bound_i(batch, n, g + 1);
        int cnt = hi - lo;
        a[t] = (cnt > 0) ? (gsum[g * 64 + t] / (float)cnt) * s + sh : 0.f;
    }
    __syncthreads();
    {
        float acc = fb1[t];
        for (int k = 0; k < 64; ++k) acc = fmaf(a[k], fW1[k * 128 + t], acc);
        bbuf[t] = fmaxf(acc, 0.f);
    }
    __syncthreads();
    if (t < 64) {
        float acc = fb2[t];
        for (int k = 0; k < 128; ++k) acc = fmaf(bbuf[k], fW2[k * 64 + t], acc);
        a[t] = fmaxf(acc, 0.f);
    }
    __syncthreads();
    if (t < 32) {
        float acc = fb3[t];
        for (int k = 0; k < 64; ++k) acc = fmaf(a[k], fW3[k * 32 + t], acc);
        bbuf[t] = fmaxf(acc, 0.f);
    }
    __syncthreads();
    if (t < 16) {
        float acc = fb4[t];
        for (int k = 0; k < 32; ++k) acc = fmaf(bbuf[k], fW4[k * 16 + t], acc);
        a[t] = fmaxf(acc, 0.f);
    }
    __syncthreads();
    if (t == 0) {
        float acc = ob[0];
        for (int k = 0; k < 16; ++k) acc = fmaf(a[k], oW[k], acc);
        out[g] = acc;
    }
}

// ---------------------------------------------------------------- launch
extern "C" void kernel_launch(void* const* d_in, const int* in_sizes, int n_in,
                              void* d_out, int out_size, void* d_ws, size_t ws_size,
                              hipStream_t stream) {
    const float* x      = (const float*)d_in[0];
    const int*   ei     = (const int*)  d_in[1];
    const int*   batch  = (const int*)  d_in[2];
    const float* W1     = (const float*)d_in[3];
    const float* b1     = (const float*)d_in[4];
    const float* W2     = (const float*)d_in[5];
    const float* b2     = (const float*)d_in[6];
    const float* gamma1 = (const float*)d_in[7];
    const float* beta1  = (const float*)d_in[8];
    const float* gamma2 = (const float*)d_in[9];
    const float* beta2  = (const float*)d_in[10];
    const float* fW1    = (const float*)d_in[11];
    const float* fb1    = (const float*)d_in[12];
    const float* fW2    = (const float*)d_in[13];
    const float* fb2    = (const float*)d_in[14];
    const float* fW3    = (const float*)d_in[15];
    const float* fb3    = (const float*)d_in[16];
    const float* fW4    = (const float*)d_in[17];
    const float* fb4    = (const float*)d_in[18];
    const float* oW     = (const float*)d_in[19];
    const float* ob     = (const float*)d_in[20];
    float* out = (float*)d_out;

    const int N = NNODES, E = NEDGES, G = NGRAPH;
    const int NB = (N + 255) / 256;

    // workspace layout (byte-based)
    char* base = (char*)d_ws;
    __half*   hd     = (__half*)base;                                 // N*64 fp16 = 12.8 MB
    float*    act    = (float*)(base + (size_t)N * 64 * 2);           // N*64 fp32 = 25.6 MB
    unsigned* indeg  = (unsigned*)((char*)act + (size_t)N * 64 * 4);  // N
    float*    dinv   = (float*)(indeg + N);                           // N
    unsigned* rowptr = (unsigned*)(dinv + N);                         // N+1
    unsigned* cursor = rowptr + (N + 1);                              // N
    unsigned* colidx = cursor + N;                                    // E
    unsigned* bsum   = colidx + E;                                    // 512
    unsigned* boff   = bsum + 512;                                    // 512
    float*    bn1s   = (float*)(boff + 512);                          // 64
    float*    bn1q   = bn1s + 64;                                     // 64
    float*    bn2s   = bn1q + 64;                                     // 64
    float*    bn2q   = bn2s + 64;                                     // 64
    float*    W2eff  = bn2q + 64;                                     // 4096
    float*    c2     = W2eff + 4096;                                  // 64
    float*    gsum   = c2 + 64;                                       // G*64

    // --- zero accumulators ---
    hipMemsetAsync(indeg, 0, (size_t)N * 4, stream);
    hipMemsetAsync(bn1s, 0, 4 * 64 * sizeof(float), stream);           // bn1s,bn1q,bn2s,bn2q
    hipMemsetAsync(gsum, 0, (size_t)G * 64 * sizeof(float), stream);

    // --- degrees + CSR scan ---
    k_count_deg<<<(E / 4 + 255) / 256, 256, 0, stream>>>(ei, indeg, E);
    k_block_reduce<<<NB, 256, 0, stream>>>(indeg, bsum, N);
    k_scan_bsum<<<1, 512, 0, stream>>>(bsum, boff, NB);
    k_scan_final<<<NB, 256, 0, stream>>>(indeg, boff, rowptr, cursor, dinv, N);

    // --- fused: GEMM1 (hd1 fp16) overlapped with CSR fill ---
    k_gemm1_fill<<<7813, 256, 0, stream>>>(x, W1, dinv, hd, ei, cursor, colidx);

    // --- layer 1 aggregate + bias + relu + BN1 stats ---
    k_gather_fused<<<(N + 127) / 128, 256, 0, stream>>>(rowptr, colidx, hd, dinv, b1, act, bn1s, bn1q, N);
    k_bn_fold_w2<<<1, 64, 0, stream>>>(bn1s, bn1q, gamma1, beta1, W2, W2eff, c2, N);

    // --- layer 2: hd2 fp16 ---
    k_gemm64_h<<<(N + 63) / 64, 256, 0, stream>>>(act, W2eff, c2, dinv, hd, N);
    k_gather_pool<<<(N + 127) / 128, 256, 0, stream>>>(rowptr, colidx, hd, dinv, b2, batch, gsum, bn2s, bn2q, N);

    // --- MLP (BN2 + pool finalize fused) ---
    k_mlp<<<G, 128, 0, stream>>>(gsum, batch, N, bn2s, bn2q, gamma2, beta2,
                                 fW1, fb1, fW2, fb2, fW3, fb3, fW4, fb4, oW, ob, out);
}